// Round 1
// baseline (3295.861 us; speedup 1.0000x reference)
//
#include <hip/hip_runtime.h>
#include <cmath>

#define NEG_SLOPE 0.2f

// ---------------------------------------------------------------- utilities
__device__ inline void atomicMaxF(float* addr, float v) {
    // works for mixed signs given init = -inf
    if (v >= 0.0f) atomicMax((int*)addr, __float_as_int(v));
    else           atomicMin((unsigned int*)addr, __float_as_uint(v));
}

__device__ inline void fma4(float acc[4], const float4 a, const float4 w0,
                            const float4 w1, const float4 w2, const float4 w3) {
    acc[0] += a.x*w0.x + a.y*w1.x + a.z*w2.x + a.w*w3.x;
    acc[1] += a.x*w0.y + a.y*w1.y + a.z*w2.y + a.w*w3.y;
    acc[2] += a.x*w0.z + a.y*w1.z + a.z*w2.z + a.w*w3.z;
    acc[3] += a.x*w0.w + a.y*w1.w + a.z*w2.w + a.w*w3.w;
}

// ---------------------------------------------------------------- init
__global__ __launch_bounds__(256) void zero_f4(float4* p, int n4) {
    int i = blockIdx.x * blockDim.x + threadIdx.x;
    int stride = gridDim.x * blockDim.x;
    float4 z = {0.f, 0.f, 0.f, 0.f};
    for (; i < n4; i += stride) p[i] = z;
}

__global__ __launch_bounds__(256) void init_sd(float* smax, float* den, int n) {
    int i = blockIdx.x * blockDim.x + threadIdx.x;
    if (i < n) { smax[i] = -INFINITY; den[i] = 0.0f; }
}

// ---------------------------------------------------------------- projection GEMM
// C[M][128] = A[M][256] @ W[256][128], fp32
__global__ __launch_bounds__(256) void gemm256x128(const float* __restrict__ A,
                                                   const float* __restrict__ W,
                                                   float* __restrict__ C, int M) {
    __shared__ float At[32][256];
    const int t  = threadIdx.x;
    const int m0 = blockIdx.x * 32;

    // stage 32x256 A tile (coalesced float4)
#pragma unroll
    for (int i = 0; i < 8; ++i) {
        int q   = t + i * 256;          // float4 index within tile
        int row = q >> 6;
        int col = (q & 63) << 2;
        float4 v = {0.f, 0.f, 0.f, 0.f};
        if (m0 + row < M) v = *(const float4*)&A[(size_t)(m0 + row) * 256 + col];
        *(float4*)&At[row][col] = v;
    }
    __syncthreads();

    const int p0 = (t >> 5) * 4;        // 8 row-groups * 4 rows
    const int n0 = (t & 31) * 4;        // 32 col-groups * 4 cols
    float acc[4][4] = {};

#pragma unroll 2
    for (int k0 = 0; k0 < 256; k0 += 4) {
        float4 a0 = *(const float4*)&At[p0 + 0][k0];
        float4 a1 = *(const float4*)&At[p0 + 1][k0];
        float4 a2 = *(const float4*)&At[p0 + 2][k0];
        float4 a3 = *(const float4*)&At[p0 + 3][k0];
        float4 w0 = *(const float4*)&W[(k0 + 0) * 128 + n0];
        float4 w1 = *(const float4*)&W[(k0 + 1) * 128 + n0];
        float4 w2 = *(const float4*)&W[(k0 + 2) * 128 + n0];
        float4 w3 = *(const float4*)&W[(k0 + 3) * 128 + n0];
        fma4(acc[0], a0, w0, w1, w2, w3);
        fma4(acc[1], a1, w0, w1, w2, w3);
        fma4(acc[2], a2, w0, w1, w2, w3);
        fma4(acc[3], a3, w0, w1, w2, w3);
    }

#pragma unroll
    for (int i = 0; i < 4; ++i) {
        int row = m0 + p0 + i;
        if (row < M) {
            float4 v = {acc[i][0], acc[i][1], acc[i][2], acc[i][3]};
            *(float4*)&C[(size_t)row * 128 + n0] = v;
        }
    }
}

// ---------------------------------------------------------------- edge score + segment max
// 32 lanes per edge: lane l -> head = l>>4, channels (l&15)*4 .. +3
__global__ __launch_bounds__(256) void edge_score(const float* __restrict__ xl,
                                                  const float* __restrict__ xr,
                                                  const int* __restrict__ esrc,
                                                  const int* __restrict__ etgt,
                                                  const float* __restrict__ att,
                                                  float* __restrict__ sc,
                                                  float* __restrict__ smax, int E) {
    int e = blockIdx.x * 8 + (threadIdx.x >> 5);
    if (e >= E) return;
    int l    = threadIdx.x & 31;
    int head = l >> 4;
    int c0   = (l & 15) << 2;
    int src  = esrc[e];
    int tgt  = etgt[e];

    const float4 xa = *(const float4*)&xl[(size_t)src * 128 + head * 64 + c0];
    const float4 xb = *(const float4*)&xr[(size_t)tgt * 128 + head * 64 + c0];
    const float4 av = *(const float4*)&att[head * 64 + c0];

    float zx = xa.x + xb.x; zx = zx > 0.f ? zx : NEG_SLOPE * zx;
    float zy = xa.y + xb.y; zy = zy > 0.f ? zy : NEG_SLOPE * zy;
    float zz = xa.z + xb.z; zz = zz > 0.f ? zz : NEG_SLOPE * zz;
    float zw = xa.w + xb.w; zw = zw > 0.f ? zw : NEG_SLOPE * zw;

    float p = zx * av.x + zy * av.y + zz * av.z + zw * av.w;
    p += __shfl_xor(p, 1);
    p += __shfl_xor(p, 2);
    p += __shfl_xor(p, 4);
    p += __shfl_xor(p, 8);

    if ((l & 15) == 0) {
        sc[(size_t)e * 2 + head] = p;
        atomicMaxF(&smax[(size_t)tgt * 2 + head], p);
    }
}

// ---------------------------------------------------------------- exp + segment sum
__global__ __launch_bounds__(256) void edge_exden(float* __restrict__ sc,
                                                  const int* __restrict__ etgt,
                                                  const float* __restrict__ smax,
                                                  float* __restrict__ den, int E2) {
    int i = blockIdx.x * 256 + threadIdx.x;
    if (i >= E2) return;
    int e = i >> 1, h = i & 1;
    int tgt  = etgt[e];
    float ex = expf(sc[i] - smax[(size_t)tgt * 2 + h]);
    sc[i] = ex;
    atomicAdd(&den[(size_t)tgt * 2 + h], ex);
}

// ---------------------------------------------------------------- weighted aggregation
__global__ __launch_bounds__(256) void edge_agg(const float* __restrict__ xl,
                                                const float* __restrict__ sc,
                                                const float* __restrict__ den,
                                                const int* __restrict__ esrc,
                                                const int* __restrict__ etgt,
                                                float* __restrict__ hout,
                                                float scale, int E) {
    int e = blockIdx.x * 8 + (threadIdx.x >> 5);
    if (e >= E) return;
    int l    = threadIdx.x & 31;
    int head = l >> 4;
    int c0   = (l & 15) << 2;
    int src  = esrc[e];
    int tgt  = etgt[e];

    float alpha = sc[(size_t)e * 2 + head] /
                  fmaxf(den[(size_t)tgt * 2 + head], 1e-16f) * scale;
    const float4 xv = *(const float4*)&xl[(size_t)src * 128 + head * 64 + c0];
    float* o = &hout[(size_t)tgt * 128 + head * 64 + c0];
    atomicAdd(o + 0, alpha * xv.x);
    atomicAdd(o + 1, alpha * xv.y);
    atomicAdd(o + 2, alpha * xv.z);
    atomicAdd(o + 3, alpha * xv.w);
}

// ---------------------------------------------------------------- pair MLP (fused)
// 32 pairs per block, 256 threads.
__global__ __launch_bounds__(256) void mlp_pairs(const float* __restrict__ h_l,
                                                 const float* __restrict__ h_m,
                                                 const int* __restrict__ pairs, int P,
                                                 const float* __restrict__ b_ll,
                                                 const float* __restrict__ b_mm,
                                                 const float* __restrict__ b_lm,
                                                 const float* __restrict__ gate_W,
                                                 const float* __restrict__ gate_b,
                                                 const float* __restrict__ c1_W,
                                                 const float* __restrict__ c1_b,
                                                 const float* __restrict__ c2_W,
                                                 const float* __restrict__ c2_b,
                                                 const float* __restrict__ c3_W,
                                                 const float* __restrict__ c3_b,
                                                 float* __restrict__ out) {
    __shared__ float fb1[32][132];
    __shared__ float fb2[32][132];
    __shared__ float fus[32][132];
    const int t  = threadIdx.x;
    const int pb = blockIdx.x * 32;

    // Phase A: gather f1/f2 (+bias fold)
    {
        int p  = t >> 3;
        int c0 = (t & 7) * 16;
        int pi = pb + p; if (pi >= P) pi = P - 1;
        int i1 = pairs[(size_t)pi * 2 + 0];
        int i2 = pairs[(size_t)pi * 2 + 1];
#pragma unroll
        for (int j = 0; j < 16; j += 4) {
            float4 v1 = *(const float4*)&h_l[(size_t)i1 * 128 + c0 + j];
            float4 bb = *(const float4*)&b_ll[c0 + j];
            v1.x += bb.x; v1.y += bb.y; v1.z += bb.z; v1.w += bb.w;
            *(float4*)&fb1[p][c0 + j] = v1;

            float4 v2 = *(const float4*)&h_m[(size_t)i2 * 128 + c0 + j];
            float4 b2 = *(const float4*)&b_mm[c0 + j];
            float4 b3 = *(const float4*)&b_lm[c0 + j];
            v2.x += 0.5f * (b2.x + b3.x);
            v2.y += 0.5f * (b2.y + b3.y);
            v2.z += 0.5f * (b2.z + b3.z);
            v2.w += 0.5f * (b2.w + b3.w);
            *(float4*)&fb2[p][c0 + j] = v2;
        }
    }
    __syncthreads();

    // Phase B: gate GEMM [32,256]@[256,128] -> g -> fused
    {
        const int p0 = (t >> 5) * 4;
        const int n0 = (t & 31) * 4;
        float acc[4][4] = {};
        for (int half = 0; half < 2; ++half) {
            const float(*fb)[132] = half ? fb2 : fb1;
            const float* Wb = gate_W + (size_t)half * 128 * 128;
#pragma unroll 2
            for (int k0 = 0; k0 < 128; k0 += 4) {
                float4 a0 = *(const float4*)&fb[p0 + 0][k0];
                float4 a1 = *(const float4*)&fb[p0 + 1][k0];
                float4 a2 = *(const float4*)&fb[p0 + 2][k0];
                float4 a3 = *(const float4*)&fb[p0 + 3][k0];
                float4 w0 = *(const float4*)&Wb[(k0 + 0) * 128 + n0];
                float4 w1 = *(const float4*)&Wb[(k0 + 1) * 128 + n0];
                float4 w2 = *(const float4*)&Wb[(k0 + 2) * 128 + n0];
                float4 w3 = *(const float4*)&Wb[(k0 + 3) * 128 + n0];
                fma4(acc[0], a0, w0, w1, w2, w3);
                fma4(acc[1], a1, w0, w1, w2, w3);
                fma4(acc[2], a2, w0, w1, w2, w3);
                fma4(acc[3], a3, w0, w1, w2, w3);
            }
        }
#pragma unroll
        for (int i = 0; i < 4; ++i) {
#pragma unroll
            for (int n = 0; n < 4; ++n) {
                float x = acc[i][n] + gate_b[n0 + n];
                float r = fmaxf(x, 0.0f);
                float g = 1.0f / (1.0f + expf(-r));
                fus[p0 + i][n0 + n] =
                    g * fb1[p0 + i][n0 + n] + (1.0f - g) * fb2[p0 + i][n0 + n];
            }
        }
    }
    __syncthreads();

    // Phase C: c1 [32,128]@[128,64] -> relu -> h1 (reuses fb1 storage, stride 68)
    float* h1 = &fb1[0][0];
    {
        const int p0 = (t >> 4) * 2;
        const int o0 = (t & 15) * 4;
        float acc[2][4] = {};
#pragma unroll 2
        for (int k0 = 0; k0 < 128; k0 += 4) {
            float4 a0 = *(const float4*)&fus[p0 + 0][k0];
            float4 a1 = *(const float4*)&fus[p0 + 1][k0];
            float4 w0 = *(const float4*)&c1_W[(k0 + 0) * 64 + o0];
            float4 w1 = *(const float4*)&c1_W[(k0 + 1) * 64 + o0];
            float4 w2 = *(const float4*)&c1_W[(k0 + 2) * 64 + o0];
            float4 w3 = *(const float4*)&c1_W[(k0 + 3) * 64 + o0];
            fma4(acc[0], a0, w0, w1, w2, w3);
            fma4(acc[1], a1, w0, w1, w2, w3);
        }
        __syncthreads();   // ensure all phase-B reads of fb1 done before overwrite
#pragma unroll
        for (int i = 0; i < 2; ++i)
#pragma unroll
            for (int n = 0; n < 4; ++n)
                h1[(p0 + i) * 68 + o0 + n] = fmaxf(acc[i][n] + c1_b[o0 + n], 0.0f);
    }
    __syncthreads();

    // Phase D: c2 [32,64]@[64,32] -> relu -> h2 (reuses fb2 storage, stride 33)
    float* h2 = &fb2[0][0];
    {
        const int p  = t >> 3;
        const int o0 = (t & 7) * 4;
        float acc[4] = {};
#pragma unroll
        for (int k0 = 0; k0 < 64; k0 += 4) {
            float4 a  = *(const float4*)&h1[p * 68 + k0];
            float4 w0 = *(const float4*)&c2_W[(k0 + 0) * 32 + o0];
            float4 w1 = *(const float4*)&c2_W[(k0 + 1) * 32 + o0];
            float4 w2 = *(const float4*)&c2_W[(k0 + 2) * 32 + o0];
            float4 w3 = *(const float4*)&c2_W[(k0 + 3) * 32 + o0];
            fma4(acc, a, w0, w1, w2, w3);
        }
        __syncthreads();   // all reads of fb2 region (phase B fused calc) long done; h1 reads done
#pragma unroll
        for (int n = 0; n < 4; ++n)
            h2[p * 33 + o0 + n] = fmaxf(acc[n] + c2_b[o0 + n], 0.0f);
    }
    __syncthreads();

    // Phase E: c3 [32,32]@[32,1]
    if (t < 32) {
        int pi = pb + t;
        if (pi < P) {
            float s = c3_b[0];
#pragma unroll
            for (int k = 0; k < 32; ++k) s += h2[t * 33 + k] * c3_W[k];
            out[pi] = s;
        }
    }
}

// ---------------------------------------------------------------- launch
extern "C" void kernel_launch(void* const* d_in, const int* in_sizes, int n_in,
                              void* d_out, int out_size, void* d_ws, size_t ws_size,
                              hipStream_t stream) {
    const float* x_lnc  = (const float*)d_in[0];
    const float* x_mi   = (const float*)d_in[1];
    const float* Wl_ll  = (const float*)d_in[2];
    const float* Wr_ll  = (const float*)d_in[3];
    const float* att_ll = (const float*)d_in[4];
    const float* b_ll   = (const float*)d_in[5];
    const float* Wl_mm  = (const float*)d_in[6];
    const float* Wr_mm  = (const float*)d_in[7];
    const float* att_mm = (const float*)d_in[8];
    const float* b_mm   = (const float*)d_in[9];
    const float* Wl_lm  = (const float*)d_in[10];
    const float* Wr_lm  = (const float*)d_in[11];
    const float* att_lm = (const float*)d_in[12];
    const float* b_lm   = (const float*)d_in[13];
    const float* gate_W = (const float*)d_in[14];
    const float* gate_b = (const float*)d_in[15];
    const float* c1_W   = (const float*)d_in[16];
    const float* c1_b   = (const float*)d_in[17];
    const float* c2_W   = (const float*)d_in[18];
    const float* c2_b   = (const float*)d_in[19];
    const float* c3_W   = (const float*)d_in[20];
    const float* c3_b   = (const float*)d_in[21];
    const int* edge_ll  = (const int*)d_in[22];
    const int* edge_mm  = (const int*)d_in[23];
    const int* edge_lm  = (const int*)d_in[24];
    const int* pairs    = (const int*)d_in[25];

    const int N = in_sizes[0] / 256;    // 30000
    const int E = in_sizes[22] / 2;     // 480000
    const int P = in_sizes[25] / 2;     // 100000

    float* ws   = (float*)d_ws;
    size_t off  = 0;
    float* h_l  = ws + off; off += (size_t)N * 128;
    float* h_m  = ws + off; off += (size_t)N * 128;
    float* xl   = ws + off; off += (size_t)N * 128;
    float* xr   = ws + off; off += (size_t)N * 128;
    float* sc   = ws + off; off += (size_t)E * 2;
    float* smax = ws + off; off += (size_t)N * 2;
    float* den  = ws + off; off += (size_t)N * 2;

    // zero h_l & h_m (contiguous)
    {
        int n4 = (N * 128 * 2) / 4;
        zero_f4<<<1024, 256, 0, stream>>>((float4*)h_l, n4);
    }

    struct Conv {
        const float *xs, *xt, *Wl, *Wr, *att;
        const int* edge;
        float* hout;
        float scale;
    };
    Conv convs[3] = {
        {x_lnc, x_lnc, Wl_ll, Wr_ll, att_ll, edge_ll, h_l, 1.0f},
        {x_mi,  x_mi,  Wl_mm, Wr_mm, att_mm, edge_mm, h_m, 0.5f},
        {x_lnc, x_mi,  Wl_lm, Wr_lm, att_lm, edge_lm, h_m, 0.5f},
    };

    const int gemm_grid = (N + 31) / 32;
    const int edge_grid = (E + 7) / 8;

    for (int c = 0; c < 3; ++c) {
        init_sd<<<(2 * N + 255) / 256, 256, 0, stream>>>(smax, den, 2 * N);
        gemm256x128<<<gemm_grid, 256, 0, stream>>>(convs[c].xs, convs[c].Wl, xl, N);
        gemm256x128<<<gemm_grid, 256, 0, stream>>>(convs[c].xt, convs[c].Wr, xr, N);
        edge_score<<<edge_grid, 256, 0, stream>>>(xl, xr, convs[c].edge,
                                                  convs[c].edge + E, convs[c].att,
                                                  sc, smax, E);
        edge_exden<<<(2 * E + 255) / 256, 256, 0, stream>>>(sc, convs[c].edge + E,
                                                            smax, den, 2 * E);
        edge_agg<<<edge_grid, 256, 0, stream>>>(xl, sc, den, convs[c].edge,
                                                convs[c].edge + E, convs[c].hout,
                                                convs[c].scale, E);
    }

    mlp_pairs<<<(P + 31) / 32, 256, 0, stream>>>(h_l, h_m, pairs, P,
                                                 b_ll, b_mm, b_lm,
                                                 gate_W, gate_b, c1_W, c1_b,
                                                 c2_W, c2_b, c3_W, c3_b,
                                                 (float*)d_out);
}

// Round 2
// 1124.234 us; speedup vs baseline: 2.9317x; 2.9317x over previous
//
#include <hip/hip_runtime.h>
#include <cmath>

#define NEG_SLOPE 0.2f

__device__ inline void fma4(float acc[4], const float4 a, const float4 w0,
                            const float4 w1, const float4 w2, const float4 w3) {
    acc[0] += a.x*w0.x + a.y*w1.x + a.z*w2.x + a.w*w3.x;
    acc[1] += a.x*w0.y + a.y*w1.y + a.z*w2.y + a.w*w3.y;
    acc[2] += a.x*w0.z + a.y*w1.z + a.z*w2.z + a.w*w3.z;
    acc[3] += a.x*w0.w + a.y*w1.w + a.z*w2.w + a.w*w3.w;
}

// ---------------------------------------------------------------- small utils
__global__ __launch_bounds__(256) void zero_int(int* p, int n) {
    int i = blockIdx.x * 256 + threadIdx.x;
    if (i < n) p[i] = 0;
}

// ---------------------------------------------------------------- CSR build
__global__ __launch_bounds__(256) void hist_tgt(const int* __restrict__ etgt,
                                                int* __restrict__ counts, int E) {
    int e = blockIdx.x * 256 + threadIdx.x;
    if (e < E) atomicAdd(&counts[etgt[e]], 1);
}

// single-block exclusive scan over counts[n] -> base[], cursor[]
__global__ __launch_bounds__(1024) void scan_counts(const int* __restrict__ counts,
                                                    int* __restrict__ base,
                                                    int* __restrict__ cursor, int n) {
    __shared__ int tot[1024];
    const int t = threadIdx.x;
    const int chunk = (n + 1023) >> 10;
    const int i0 = t * chunk;
    int s = 0;
    for (int i = 0; i < chunk; ++i) {
        int idx = i0 + i;
        if (idx < n) s += counts[idx];
    }
    tot[t] = s;
    __syncthreads();
    for (int d = 1; d < 1024; d <<= 1) {
        int v = (t >= d) ? tot[t - d] : 0;
        __syncthreads();
        tot[t] += v;
        __syncthreads();
    }
    int run = (t == 0) ? 0 : tot[t - 1];
    for (int i = 0; i < chunk; ++i) {
        int idx = i0 + i;
        if (idx < n) {
            base[idx]   = run;
            cursor[idx] = run;
            run += counts[idx];
        }
    }
}

__global__ __launch_bounds__(256) void scatter_edges(const int* __restrict__ esrc,
                                                     const int* __restrict__ etgt,
                                                     int* __restrict__ cursor,
                                                     int* __restrict__ perm, int E) {
    int e = blockIdx.x * 256 + threadIdx.x;
    if (e >= E) return;
    int pos = atomicAdd(&cursor[etgt[e]], 1);
    perm[pos] = esrc[e];
}

// ---------------------------------------------------------------- projection GEMM
// C[M][128] = A[M][256] @ W[256][128], fp32
__global__ __launch_bounds__(256) void gemm256x128(const float* __restrict__ A,
                                                   const float* __restrict__ W,
                                                   float* __restrict__ C, int M) {
    __shared__ float At[32][256];
    const int t  = threadIdx.x;
    const int m0 = blockIdx.x * 32;

#pragma unroll
    for (int i = 0; i < 8; ++i) {
        int q   = t + i * 256;
        int row = q >> 6;
        int col = (q & 63) << 2;
        float4 v = {0.f, 0.f, 0.f, 0.f};
        if (m0 + row < M) v = *(const float4*)&A[(size_t)(m0 + row) * 256 + col];
        *(float4*)&At[row][col] = v;
    }
    __syncthreads();

    const int p0 = (t >> 5) * 4;
    const int n0 = (t & 31) * 4;
    float acc[4][4] = {};

#pragma unroll 2
    for (int k0 = 0; k0 < 256; k0 += 4) {
        float4 a0 = *(const float4*)&At[p0 + 0][k0];
        float4 a1 = *(const float4*)&At[p0 + 1][k0];
        float4 a2 = *(const float4*)&At[p0 + 2][k0];
        float4 a3 = *(const float4*)&At[p0 + 3][k0];
        float4 w0 = *(const float4*)&W[(k0 + 0) * 128 + n0];
        float4 w1 = *(const float4*)&W[(k0 + 1) * 128 + n0];
        float4 w2 = *(const float4*)&W[(k0 + 2) * 128 + n0];
        float4 w3 = *(const float4*)&W[(k0 + 3) * 128 + n0];
        fma4(acc[0], a0, w0, w1, w2, w3);
        fma4(acc[1], a1, w0, w1, w2, w3);
        fma4(acc[2], a2, w0, w1, w2, w3);
        fma4(acc[3], a3, w0, w1, w2, w3);
    }

#pragma unroll
    for (int i = 0; i < 4; ++i) {
        int row = m0 + p0 + i;
        if (row < M) {
            float4 v = {acc[i][0], acc[i][1], acc[i][2], acc[i][3]};
            *(float4*)&C[(size_t)row * 128 + n0] = v;
        }
    }
}

// ---------------------------------------------------------------- fused per-node GATv2
// One 64-lane wave per target node. lane l covers channels (2l, 2l+1);
// head = l>>5. Online softmax over the node's CSR edge list; zero atomics.
// MODE 0: hout = agg            (scale 1.0)
// MODE 1: hout = 0.5*agg        (store)
// MODE 2: hout += 0.5*agg       (accumulate, wave owns the row -> plain RMW)
template <int MODE>
__global__ __launch_bounds__(256) void node_gatv2(const float* __restrict__ xl,
                                                  const float* __restrict__ xr,
                                                  const float* __restrict__ att,
                                                  const int* __restrict__ base,
                                                  const int* __restrict__ counts,
                                                  const int* __restrict__ perm,
                                                  float* __restrict__ hout, int N) {
    const int node = blockIdx.x * 4 + (threadIdx.x >> 6);
    if (node >= N) return;
    const int l = threadIdx.x & 63;

    const float2 xrv  = *(const float2*)&xr[(size_t)node * 128 + l * 2];
    const float2 attv = *(const float2*)&att[l * 2];
    const int b   = base[node];
    const int deg = counts[node];

    float  m   = -INFINITY;
    float  den = 0.0f;
    float2 acc = {0.0f, 0.0f};

    for (int k = 0; k < deg; ++k) {
        int src = perm[b + k];
        float2 x = *(const float2*)&xl[(size_t)src * 128 + l * 2];
        float zx = x.x + xrv.x; zx = zx > 0.f ? zx : NEG_SLOPE * zx;
        float zy = x.y + xrv.y; zy = zy > 0.f ? zy : NEG_SLOPE * zy;
        float p = zx * attv.x + zy * attv.y;
        p += __shfl_xor(p, 1);
        p += __shfl_xor(p, 2);
        p += __shfl_xor(p, 4);
        p += __shfl_xor(p, 8);
        p += __shfl_xor(p, 16);        // lanes 0-31: s_head0, lanes 32-63: s_head1

        float mn  = fmaxf(m, p);
        float fct = expf(m - mn);      // m=-inf first iter -> 0
        float ex  = expf(p - mn);
        den   = den * fct + ex;
        acc.x = acc.x * fct + ex * x.x;
        acc.y = acc.y * fct + ex * x.y;
        m = mn;
    }

    const float scale = (MODE == 0) ? 1.0f : 0.5f;
    const float r = scale / fmaxf(den, 1e-16f);
    float2 o = {acc.x * r, acc.y * r};
    float* dst = &hout[(size_t)node * 128 + l * 2];
    if (MODE == 2) {
        float2 prev = *(const float2*)dst;
        o.x += prev.x; o.y += prev.y;
    }
    *(float2*)dst = o;
}

// ---------------------------------------------------------------- pair MLP (fused)
__global__ __launch_bounds__(256) void mlp_pairs(const float* __restrict__ h_l,
                                                 const float* __restrict__ h_m,
                                                 const int* __restrict__ pairs, int P,
                                                 const float* __restrict__ b_ll,
                                                 const float* __restrict__ b_mm,
                                                 const float* __restrict__ b_lm,
                                                 const float* __restrict__ gate_W,
                                                 const float* __restrict__ gate_b,
                                                 const float* __restrict__ c1_W,
                                                 const float* __restrict__ c1_b,
                                                 const float* __restrict__ c2_W,
                                                 const float* __restrict__ c2_b,
                                                 const float* __restrict__ c3_W,
                                                 const float* __restrict__ c3_b,
                                                 float* __restrict__ out) {
    __shared__ float fb1[32][132];
    __shared__ float fb2[32][132];
    __shared__ float fus[32][132];
    const int t  = threadIdx.x;
    const int pb = blockIdx.x * 32;

    // Phase A: gather f1/f2 (+bias fold)
    {
        int p  = t >> 3;
        int c0 = (t & 7) * 16;
        int pi = pb + p; if (pi >= P) pi = P - 1;
        int i1 = pairs[(size_t)pi * 2 + 0];
        int i2 = pairs[(size_t)pi * 2 + 1];
#pragma unroll
        for (int j = 0; j < 16; j += 4) {
            float4 v1 = *(const float4*)&h_l[(size_t)i1 * 128 + c0 + j];
            float4 bb = *(const float4*)&b_ll[c0 + j];
            v1.x += bb.x; v1.y += bb.y; v1.z += bb.z; v1.w += bb.w;
            *(float4*)&fb1[p][c0 + j] = v1;

            float4 v2 = *(const float4*)&h_m[(size_t)i2 * 128 + c0 + j];
            float4 b2 = *(const float4*)&b_mm[c0 + j];
            float4 b3 = *(const float4*)&b_lm[c0 + j];
            v2.x += 0.5f * (b2.x + b3.x);
            v2.y += 0.5f * (b2.y + b3.y);
            v2.z += 0.5f * (b2.z + b3.z);
            v2.w += 0.5f * (b2.w + b3.w);
            *(float4*)&fb2[p][c0 + j] = v2;
        }
    }
    __syncthreads();

    // Phase B: gate GEMM [32,256]@[256,128] -> g -> fused
    {
        const int p0 = (t >> 5) * 4;
        const int n0 = (t & 31) * 4;
        float acc[4][4] = {};
        for (int half = 0; half < 2; ++half) {
            const float(*fb)[132] = half ? fb2 : fb1;
            const float* Wb = gate_W + (size_t)half * 128 * 128;
#pragma unroll 2
            for (int k0 = 0; k0 < 128; k0 += 4) {
                float4 a0 = *(const float4*)&fb[p0 + 0][k0];
                float4 a1 = *(const float4*)&fb[p0 + 1][k0];
                float4 a2 = *(const float4*)&fb[p0 + 2][k0];
                float4 a3 = *(const float4*)&fb[p0 + 3][k0];
                float4 w0 = *(const float4*)&Wb[(k0 + 0) * 128 + n0];
                float4 w1 = *(const float4*)&Wb[(k0 + 1) * 128 + n0];
                float4 w2 = *(const float4*)&Wb[(k0 + 2) * 128 + n0];
                float4 w3 = *(const float4*)&Wb[(k0 + 3) * 128 + n0];
                fma4(acc[0], a0, w0, w1, w2, w3);
                fma4(acc[1], a1, w0, w1, w2, w3);
                fma4(acc[2], a2, w0, w1, w2, w3);
                fma4(acc[3], a3, w0, w1, w2, w3);
            }
        }
#pragma unroll
        for (int i = 0; i < 4; ++i) {
#pragma unroll
            for (int n = 0; n < 4; ++n) {
                float x = acc[i][n] + gate_b[n0 + n];
                float r = fmaxf(x, 0.0f);
                float g = 1.0f / (1.0f + expf(-r));
                fus[p0 + i][n0 + n] =
                    g * fb1[p0 + i][n0 + n] + (1.0f - g) * fb2[p0 + i][n0 + n];
            }
        }
    }
    __syncthreads();

    // Phase C: c1 [32,128]@[128,64] -> relu -> h1 (reuses fb1, stride 68)
    float* h1 = &fb1[0][0];
    {
        const int p0 = (t >> 4) * 2;
        const int o0 = (t & 15) * 4;
        float acc[2][4] = {};
#pragma unroll 2
        for (int k0 = 0; k0 < 128; k0 += 4) {
            float4 a0 = *(const float4*)&fus[p0 + 0][k0];
            float4 a1 = *(const float4*)&fus[p0 + 1][k0];
            float4 w0 = *(const float4*)&c1_W[(k0 + 0) * 64 + o0];
            float4 w1 = *(const float4*)&c1_W[(k0 + 1) * 64 + o0];
            float4 w2 = *(const float4*)&c1_W[(k0 + 2) * 64 + o0];
            float4 w3 = *(const float4*)&c1_W[(k0 + 3) * 64 + o0];
            fma4(acc[0], a0, w0, w1, w2, w3);
            fma4(acc[1], a1, w0, w1, w2, w3);
        }
        __syncthreads();
#pragma unroll
        for (int i = 0; i < 2; ++i)
#pragma unroll
            for (int n = 0; n < 4; ++n)
                h1[(p0 + i) * 68 + o0 + n] = fmaxf(acc[i][n] + c1_b[o0 + n], 0.0f);
    }
    __syncthreads();

    // Phase D: c2 [32,64]@[64,32] -> relu -> h2 (reuses fb2, stride 33)
    float* h2 = &fb2[0][0];
    {
        const int p  = t >> 3;
        const int o0 = (t & 7) * 4;
        float acc[4] = {};
#pragma unroll
        for (int k0 = 0; k0 < 64; k0 += 4) {
            float4 a  = *(const float4*)&h1[p * 68 + k0];
            float4 w0 = *(const float4*)&c2_W[(k0 + 0) * 32 + o0];
            float4 w1 = *(const float4*)&c2_W[(k0 + 1) * 32 + o0];
            float4 w2 = *(const float4*)&c2_W[(k0 + 2) * 32 + o0];
            float4 w3 = *(const float4*)&c2_W[(k0 + 3) * 32 + o0];
            fma4(acc, a, w0, w1, w2, w3);
        }
        __syncthreads();
#pragma unroll
        for (int n = 0; n < 4; ++n)
            h2[p * 33 + o0 + n] = fmaxf(acc[n] + c2_b[o0 + n], 0.0f);
    }
    __syncthreads();

    // Phase E: c3 [32,32]@[32,1]
    if (t < 32) {
        int pi = pb + t;
        if (pi < P) {
            float s = c3_b[0];
#pragma unroll
            for (int k = 0; k < 32; ++k) s += h2[t * 33 + k] * c3_W[k];
            out[pi] = s;
        }
    }
}

// ---------------------------------------------------------------- launch
extern "C" void kernel_launch(void* const* d_in, const int* in_sizes, int n_in,
                              void* d_out, int out_size, void* d_ws, size_t ws_size,
                              hipStream_t stream) {
    const float* x_lnc  = (const float*)d_in[0];
    const float* x_mi   = (const float*)d_in[1];
    const float* Wl_ll  = (const float*)d_in[2];
    const float* Wr_ll  = (const float*)d_in[3];
    const float* att_ll = (const float*)d_in[4];
    const float* b_ll   = (const float*)d_in[5];
    const float* Wl_mm  = (const float*)d_in[6];
    const float* Wr_mm  = (const float*)d_in[7];
    const float* att_mm = (const float*)d_in[8];
    const float* b_mm   = (const float*)d_in[9];
    const float* Wl_lm  = (const float*)d_in[10];
    const float* Wr_lm  = (const float*)d_in[11];
    const float* att_lm = (const float*)d_in[12];
    const float* b_lm   = (const float*)d_in[13];
    const float* gate_W = (const float*)d_in[14];
    const float* gate_b = (const float*)d_in[15];
    const float* c1_W   = (const float*)d_in[16];
    const float* c1_b   = (const float*)d_in[17];
    const float* c2_W   = (const float*)d_in[18];
    const float* c2_b   = (const float*)d_in[19];
    const float* c3_W   = (const float*)d_in[20];
    const float* c3_b   = (const float*)d_in[21];
    const int* edge_ll  = (const int*)d_in[22];
    const int* edge_mm  = (const int*)d_in[23];
    const int* edge_lm  = (const int*)d_in[24];
    const int* pairs    = (const int*)d_in[25];

    const int N = in_sizes[0] / 256;    // 30000
    const int E = in_sizes[22] / 2;     // 480000
    const int P = in_sizes[25] / 2;     // 100000

    float* ws  = (float*)d_ws;
    size_t off = 0;
    float* h_l  = ws + off; off += (size_t)N * 128;
    float* h_m  = ws + off; off += (size_t)N * 128;
    float* xl   = ws + off; off += (size_t)N * 128;
    float* xr   = ws + off; off += (size_t)N * 128;
    int* perm   = (int*)(ws + off); off += (size_t)E;
    int* counts = (int*)(ws + off); off += (size_t)N;
    int* base   = (int*)(ws + off); off += (size_t)N;
    int* cursor = (int*)(ws + off); off += (size_t)N;

    struct Conv {
        const float *xs, *xt, *Wl, *Wr, *att;
        const int* edge;
    };
    Conv convs[3] = {
        {x_lnc, x_lnc, Wl_ll, Wr_ll, att_ll, edge_ll},
        {x_mi,  x_mi,  Wl_mm, Wr_mm, att_mm, edge_mm},
        {x_lnc, x_mi,  Wl_lm, Wr_lm, att_lm, edge_lm},
    };

    const int gemm_grid = (N + 31) / 32;
    const int egrid     = (E + 255) / 256;
    const int ngrid     = (N + 255) / 256;
    const int node_grid = (N + 3) / 4;

    for (int c = 0; c < 3; ++c) {
        const Conv& cv = convs[c];
        // CSR build
        zero_int<<<ngrid, 256, 0, stream>>>(counts, N);
        hist_tgt<<<egrid, 256, 0, stream>>>(cv.edge + E, counts, E);
        scan_counts<<<1, 1024, 0, stream>>>(counts, base, cursor, N);
        scatter_edges<<<egrid, 256, 0, stream>>>(cv.edge, cv.edge + E, cursor, perm, E);
        // projections
        gemm256x128<<<gemm_grid, 256, 0, stream>>>(cv.xs, cv.Wl, xl, N);
        gemm256x128<<<gemm_grid, 256, 0, stream>>>(cv.xt, cv.Wr, xr, N);
        // fused softmax + aggregation
        if (c == 0)
            node_gatv2<0><<<node_grid, 256, 0, stream>>>(xl, xr, att_ll, base, counts,
                                                         perm, h_l, N);
        else if (c == 1)
            node_gatv2<1><<<node_grid, 256, 0, stream>>>(xl, xr, att_mm, base, counts,
                                                         perm, h_m, N);
        else
            node_gatv2<2><<<node_grid, 256, 0, stream>>>(xl, xr, att_lm, base, counts,
                                                         perm, h_m, N);
    }

    mlp_pairs<<<(P + 31) / 32, 256, 0, stream>>>(h_l, h_m, pairs, P,
                                                 b_ll, b_mm, b_lm,
                                                 gate_W, gate_b, c1_W, c1_b,
                                                 c2_W, c2_b, c3_W, c3_b,
                                                 (float*)d_out);
}

// Round 4
// 1093.564 us; speedup vs baseline: 3.0139x; 1.0280x over previous
//
#include <hip/hip_runtime.h>
#include <cmath>

#define NEG_SLOPE 0.2f

__device__ inline void fma4(float acc[4], const float4 a, const float4 w0,
                            const float4 w1, const float4 w2, const float4 w3) {
    acc[0] += a.x*w0.x + a.y*w1.x + a.z*w2.x + a.w*w3.x;
    acc[1] += a.x*w0.y + a.y*w1.y + a.z*w2.y + a.w*w3.y;
    acc[2] += a.x*w0.z + a.y*w1.z + a.z*w2.z + a.w*w3.z;
    acc[3] += a.x*w0.w + a.y*w1.w + a.z*w2.w + a.w*w3.w;
}

// ---------------------------------------------------------------- small utils
__global__ __launch_bounds__(256) void zero_int(int* p, int n) {
    int i = blockIdx.x * 256 + threadIdx.x;
    if (i < n) p[i] = 0;
}

// ---------------------------------------------------------------- CSR build
__global__ __launch_bounds__(256) void hist_tgt(const int* __restrict__ etgt,
                                                int* __restrict__ counts, int E) {
    int e = blockIdx.x * 256 + threadIdx.x;
    if (e < E) atomicAdd(&counts[etgt[e]], 1);
}

__global__ __launch_bounds__(1024) void scan_counts(const int* __restrict__ counts,
                                                    int* __restrict__ base,
                                                    int* __restrict__ cursor, int n) {
    __shared__ int tot[1024];
    const int t = threadIdx.x;
    const int chunk = (n + 1023) >> 10;
    const int i0 = t * chunk;
    int s = 0;
    for (int i = 0; i < chunk; ++i) {
        int idx = i0 + i;
        if (idx < n) s += counts[idx];
    }
    tot[t] = s;
    __syncthreads();
    for (int d = 1; d < 1024; d <<= 1) {
        int v = (t >= d) ? tot[t - d] : 0;
        __syncthreads();
        tot[t] += v;
        __syncthreads();
    }
    int run = (t == 0) ? 0 : tot[t - 1];
    for (int i = 0; i < chunk; ++i) {
        int idx = i0 + i;
        if (idx < n) {
            base[idx]   = run;
            cursor[idx] = run;
            run += counts[idx];
        }
    }
}

__global__ __launch_bounds__(256) void scatter_edges(const int* __restrict__ esrc,
                                                     const int* __restrict__ etgt,
                                                     int* __restrict__ cursor,
                                                     int* __restrict__ perm, int E) {
    int e = blockIdx.x * 256 + threadIdx.x;
    if (e >= E) return;
    int pos = atomicAdd(&cursor[etgt[e]], 1);
    perm[pos] = esrc[e];
}

// ---------------------------------------------------------------- projection GEMMs
// C[M][128] = A[M][256] @ W[256][128], fp32; DUAL variant shares the A tile.
template <int NW>
__global__ __launch_bounds__(256) void gemm256x128_t(const float* __restrict__ A,
                                                     const float* __restrict__ W1,
                                                     const float* __restrict__ W2,
                                                     float* __restrict__ C1,
                                                     float* __restrict__ C2, int M) {
    __shared__ float At[32][256];
    const int t  = threadIdx.x;
    const int m0 = blockIdx.x * 32;

#pragma unroll
    for (int i = 0; i < 8; ++i) {
        int q   = t + i * 256;
        int row = q >> 6;
        int col = (q & 63) << 2;
        float4 v = {0.f, 0.f, 0.f, 0.f};
        if (m0 + row < M) v = *(const float4*)&A[(size_t)(m0 + row) * 256 + col];
        *(float4*)&At[row][col] = v;
    }
    __syncthreads();

    const int p0 = (t >> 5) * 4;
    const int n0 = (t & 31) * 4;

#pragma unroll
    for (int ph = 0; ph < NW; ++ph) {
        const float* __restrict__ W = ph ? W2 : W1;
        float* __restrict__ C       = ph ? C2 : C1;
        float acc[4][4] = {};
#pragma unroll 2
        for (int k0 = 0; k0 < 256; k0 += 4) {
            float4 a0 = *(const float4*)&At[p0 + 0][k0];
            float4 a1 = *(const float4*)&At[p0 + 1][k0];
            float4 a2 = *(const float4*)&At[p0 + 2][k0];
            float4 a3 = *(const float4*)&At[p0 + 3][k0];
            float4 w0 = *(const float4*)&W[(k0 + 0) * 128 + n0];
            float4 w1 = *(const float4*)&W[(k0 + 1) * 128 + n0];
            float4 w2 = *(const float4*)&W[(k0 + 2) * 128 + n0];
            float4 w3 = *(const float4*)&W[(k0 + 3) * 128 + n0];
            fma4(acc[0], a0, w0, w1, w2, w3);
            fma4(acc[1], a1, w0, w1, w2, w3);
            fma4(acc[2], a2, w0, w1, w2, w3);
            fma4(acc[3], a3, w0, w1, w2, w3);
        }
#pragma unroll
        for (int i = 0; i < 4; ++i) {
            int row = m0 + p0 + i;
            if (row < M) {
                float4 v = {acc[i][0], acc[i][1], acc[i][2], acc[i][3]};
                *(float4*)&C[(size_t)row * 128 + n0] = v;
            }
        }
    }
}

// ---------------------------------------------------------------- fused per-node GATv2
// One 64-lane wave per target node; lane l covers channels (2l,2l+1); head=l>>5.
// 4-edge unrolled online softmax; zero atomics.
// MODE 0: hout = agg ; MODE 1: hout = 0.5*agg ; MODE 2: hout += 0.5*agg
#define LEAKY(z) ((z) > 0.f ? (z) : NEG_SLOPE * (z))
#define WREDUCE(p) { p += __shfl_xor(p, 1); p += __shfl_xor(p, 2); \
                     p += __shfl_xor(p, 4); p += __shfl_xor(p, 8); \
                     p += __shfl_xor(p, 16); }

template <int MODE>
__global__ __launch_bounds__(256) void node_gatv2(const float* __restrict__ xl,
                                                  const float* __restrict__ xr,
                                                  const float* __restrict__ att,
                                                  const int* __restrict__ base,
                                                  const int* __restrict__ counts,
                                                  const int* __restrict__ perm,
                                                  float* __restrict__ hout, int N) {
    const int node = blockIdx.x * 4 + (threadIdx.x >> 6);
    if (node >= N) return;
    const int l = threadIdx.x & 63;

    const float2 xrv  = *(const float2*)&xr[(size_t)node * 128 + l * 2];
    const float2 attv = *(const float2*)&att[l * 2];
    const int b   = base[node];
    const int deg = counts[node];

    float  m   = -INFINITY;
    float  den = 0.0f;
    float2 acc = {0.0f, 0.0f};

    int k = 0;
    for (; k + 3 < deg; k += 4) {
        int s0 = perm[b + k + 0];
        int s1 = perm[b + k + 1];
        int s2 = perm[b + k + 2];
        int s3 = perm[b + k + 3];
        float2 x0 = *(const float2*)&xl[(size_t)s0 * 128 + l * 2];
        float2 x1 = *(const float2*)&xl[(size_t)s1 * 128 + l * 2];
        float2 x2 = *(const float2*)&xl[(size_t)s2 * 128 + l * 2];
        float2 x3 = *(const float2*)&xl[(size_t)s3 * 128 + l * 2];

        float p0 = LEAKY(x0.x + xrv.x) * attv.x + LEAKY(x0.y + xrv.y) * attv.y;
        float p1 = LEAKY(x1.x + xrv.x) * attv.x + LEAKY(x1.y + xrv.y) * attv.y;
        float p2 = LEAKY(x2.x + xrv.x) * attv.x + LEAKY(x2.y + xrv.y) * attv.y;
        float p3 = LEAKY(x3.x + xrv.x) * attv.x + LEAKY(x3.y + xrv.y) * attv.y;
        WREDUCE(p0) WREDUCE(p1) WREDUCE(p2) WREDUCE(p3)

        float mn = fmaxf(fmaxf(fmaxf(m, p0), fmaxf(p1, p2)), p3);
        float f  = expf(m  - mn);
        float e0 = expf(p0 - mn);
        float e1 = expf(p1 - mn);
        float e2 = expf(p2 - mn);
        float e3 = expf(p3 - mn);
        den   = den   * f + e0 + e1 + e2 + e3;
        acc.x = acc.x * f + e0 * x0.x + e1 * x1.x + e2 * x2.x + e3 * x3.x;
        acc.y = acc.y * f + e0 * x0.y + e1 * x1.y + e2 * x2.y + e3 * x3.y;
        m = mn;
    }
    for (; k < deg; ++k) {
        int src = perm[b + k];
        float2 x = *(const float2*)&xl[(size_t)src * 128 + l * 2];
        float p = LEAKY(x.x + xrv.x) * attv.x + LEAKY(x.y + xrv.y) * attv.y;
        WREDUCE(p)
        float mn = fmaxf(m, p);
        float f  = expf(m - mn);
        float ex = expf(p - mn);
        den   = den   * f + ex;
        acc.x = acc.x * f + ex * x.x;
        acc.y = acc.y * f + ex * x.y;
        m = mn;
    }

    const float scale = (MODE == 0) ? 1.0f : 0.5f;
    const float r = scale / fmaxf(den, 1e-16f);
    float2 o = {acc.x * r, acc.y * r};
    float* dst = &hout[(size_t)node * 128 + l * 2];
    if (MODE == 2) {
        float2 prev = *(const float2*)dst;
        o.x += prev.x; o.y += prev.y;
    }
    *(float2*)dst = o;
}

// ---------------------------------------------------------------- pair MLP (fused)
// 32 pairs/block, 256 threads, 2 LDS buffers (33.8 KB) -> 4 blocks/CU.
__global__ __launch_bounds__(256, 4) void mlp_pairs(const float* __restrict__ h_l,
                                                    const float* __restrict__ h_m,
                                                    const int* __restrict__ pairs, int P,
                                                    const float* __restrict__ b_ll,
                                                    const float* __restrict__ b_mm,
                                                    const float* __restrict__ b_lm,
                                                    const float* __restrict__ gate_W,
                                                    const float* __restrict__ gate_b,
                                                    const float* __restrict__ c1_W,
                                                    const float* __restrict__ c1_b,
                                                    const float* __restrict__ c2_W,
                                                    const float* __restrict__ c2_b,
                                                    const float* __restrict__ c3_W,
                                                    const float* __restrict__ c3_b,
                                                    float* __restrict__ out) {
    __shared__ float fb1[32][132];
    __shared__ float fb2[32][132];
    const int t  = threadIdx.x;
    const int pb = blockIdx.x * 32;

    // Phase A: gather f1/f2 (+bias fold)
    {
        int p  = t >> 3;
        int c0 = (t & 7) * 16;
        int pi = pb + p; if (pi >= P) pi = P - 1;
        int i1 = pairs[(size_t)pi * 2 + 0];
        int i2 = pairs[(size_t)pi * 2 + 1];
#pragma unroll
        for (int j = 0; j < 16; j += 4) {
            float4 v1 = *(const float4*)&h_l[(size_t)i1 * 128 + c0 + j];
            float4 bb = *(const float4*)&b_ll[c0 + j];
            v1.x += bb.x; v1.y += bb.y; v1.z += bb.z; v1.w += bb.w;
            *(float4*)&fb1[p][c0 + j] = v1;

            float4 v2 = *(const float4*)&h_m[(size_t)i2 * 128 + c0 + j];
            float4 b2 = *(const float4*)&b_mm[c0 + j];
            float4 b3 = *(const float4*)&b_lm[c0 + j];
            v2.x += 0.5f * (b2.x + b3.x);
            v2.y += 0.5f * (b2.y + b3.y);
            v2.z += 0.5f * (b2.z + b3.z);
            v2.w += 0.5f * (b2.w + b3.w);
            *(float4*)&fb2[p][c0 + j] = v2;
        }
    }
    __syncthreads();

    // Phase B: gate GEMM [32,256]@[256,128] -> g -> fused (in-place into fb1)
    {
        const int p0 = (t >> 5) * 4;
        const int n0 = (t & 31) * 4;
        float acc[4][4] = {};
        for (int half = 0; half < 2; ++half) {
            const float(*fb)[132] = half ? fb2 : fb1;
            const float* Wb = gate_W + (size_t)half * 128 * 128;
#pragma unroll 2
            for (int k0 = 0; k0 < 128; k0 += 4) {
                float4 a0 = *(const float4*)&fb[p0 + 0][k0];
                float4 a1 = *(const float4*)&fb[p0 + 1][k0];
                float4 a2 = *(const float4*)&fb[p0 + 2][k0];
                float4 a3 = *(const float4*)&fb[p0 + 3][k0];
                float4 w0 = *(const float4*)&Wb[(k0 + 0) * 128 + n0];
                float4 w1 = *(const float4*)&Wb[(k0 + 1) * 128 + n0];
                float4 w2 = *(const float4*)&Wb[(k0 + 2) * 128 + n0];
                float4 w3 = *(const float4*)&Wb[(k0 + 3) * 128 + n0];
                fma4(acc[0], a0, w0, w1, w2, w3);
                fma4(acc[1], a1, w0, w1, w2, w3);
                fma4(acc[2], a2, w0, w1, w2, w3);
                fma4(acc[3], a3, w0, w1, w2, w3);
            }
        }
        __syncthreads();   // all GEMM reads of fb1/fb2 done
#pragma unroll
        for (int i = 0; i < 4; ++i) {
#pragma unroll
            for (int n = 0; n < 4; ++n) {
                float x = acc[i][n] + gate_b[n0 + n];
                float r = fmaxf(x, 0.0f);
                float g = 1.0f / (1.0f + expf(-r));
                fb1[p0 + i][n0 + n] =
                    g * fb1[p0 + i][n0 + n] + (1.0f - g) * fb2[p0 + i][n0 + n];
            }
        }
    }
    __syncthreads();

    // Phase C: c1 [32,128]@[128,64] -> relu -> h1 (into fb2 region, stride 68)
    float* h1 = &fb2[0][0];
    {
        const int p0 = (t >> 4) * 2;
        const int o0 = (t & 15) * 4;
        float acc[2][4] = {};
#pragma unroll 2
        for (int k0 = 0; k0 < 128; k0 += 4) {
            float4 a0 = *(const float4*)&fb1[p0 + 0][k0];
            float4 a1 = *(const float4*)&fb1[p0 + 1][k0];
            float4 w0 = *(const float4*)&c1_W[(k0 + 0) * 64 + o0];
            float4 w1 = *(const float4*)&c1_W[(k0 + 1) * 64 + o0];
            float4 w2 = *(const float4*)&c1_W[(k0 + 2) * 64 + o0];
            float4 w3 = *(const float4*)&c1_W[(k0 + 3) * 64 + o0];
            fma4(acc[0], a0, w0, w1, w2, w3);
            fma4(acc[1], a1, w0, w1, w2, w3);
        }
        // fb2 reads all finished before last barrier; safe to overwrite
#pragma unroll
        for (int i = 0; i < 2; ++i)
#pragma unroll
            for (int n = 0; n < 4; ++n)
                h1[(p0 + i) * 68 + o0 + n] = fmaxf(acc[i][n] + c1_b[o0 + n], 0.0f);
    }
    __syncthreads();

    // Phase D: c2 [32,64]@[64,32] -> relu -> h2 (into fb1 region, stride 33)
    float* h2 = &fb1[0][0];
    {
        const int p  = t >> 3;
        const int o0 = (t & 7) * 4;
        float acc[4] = {};
#pragma unroll
        for (int k0 = 0; k0 < 64; k0 += 4) {
            float4 a  = *(const float4*)&h1[p * 68 + k0];
            float4 w0 = *(const float4*)&c2_W[(k0 + 0) * 32 + o0];
            float4 w1 = *(const float4*)&c2_W[(k0 + 1) * 32 + o0];
            float4 w2 = *(const float4*)&c2_W[(k0 + 2) * 32 + o0];
            float4 w3 = *(const float4*)&c2_W[(k0 + 3) * 32 + o0];
            fma4(acc, a, w0, w1, w2, w3);
        }
        __syncthreads();   // fb1 GEMM reads (phase C) done before overwrite
#pragma unroll
        for (int n = 0; n < 4; ++n)
            h2[p * 33 + o0 + n] = fmaxf(acc[n] + c2_b[o0 + n], 0.0f);
    }
    __syncthreads();

    // Phase E: c3 [32,32]@[32,1]
    if (t < 32) {
        int pi = pb + t;
        if (pi < P) {
            float s = c3_b[0];
#pragma unroll
            for (int k = 0; k < 32; ++k) s += h2[t * 33 + k] * c3_W[k];
            out[pi] = s;
        }
    }
}

// ---------------------------------------------------------------- launch
extern "C" void kernel_launch(void* const* d_in, const int* in_sizes, int n_in,
                              void* d_out, int out_size, void* d_ws, size_t ws_size,
                              hipStream_t stream) {
    const float* x_lnc  = (const float*)d_in[0];
    const float* x_mi   = (const float*)d_in[1];
    const float* Wl_ll  = (const float*)d_in[2];
    const float* Wr_ll  = (const float*)d_in[3];
    const float* att_ll = (const float*)d_in[4];
    const float* b_ll   = (const float*)d_in[5];
    const float* Wl_mm  = (const float*)d_in[6];
    const float* Wr_mm  = (const float*)d_in[7];
    const float* att_mm = (const float*)d_in[8];
    const float* b_mm   = (const float*)d_in[9];
    const float* Wl_lm  = (const float*)d_in[10];
    const float* Wr_lm  = (const float*)d_in[11];
    const float* att_lm = (const float*)d_in[12];
    const float* b_lm   = (const float*)d_in[13];
    const float* gate_W = (const float*)d_in[14];
    const float* gate_b = (const float*)d_in[15];
    const float* c1_W   = (const float*)d_in[16];
    const float* c1_b   = (const float*)d_in[17];
    const float* c2_W   = (const float*)d_in[18];
    const float* c2_b   = (const float*)d_in[19];
    const float* c3_W   = (const float*)d_in[20];
    const float* c3_b   = (const float*)d_in[21];
    const int* edge_ll  = (const int*)d_in[22];
    const int* edge_mm  = (const int*)d_in[23];
    const int* edge_lm  = (const int*)d_in[24];
    const int* pairs    = (const int*)d_in[25];

    const int N = in_sizes[0] / 256;    // 30000
    const int E = in_sizes[22] / 2;     // 480000
    const int P = in_sizes[25] / 2;     // 100000

    float* ws  = (float*)d_ws;
    size_t off = 0;
    float* h_l  = ws + off; off += (size_t)N * 128;
    float* h_m  = ws + off; off += (size_t)N * 128;
    float* xl   = ws + off; off += (size_t)N * 128;
    float* xr   = ws + off; off += (size_t)N * 128;
    int* perm   = (int*)(ws + off); off += (size_t)E;
    int* counts = (int*)(ws + off); off += (size_t)N;
    int* base   = (int*)(ws + off); off += (size_t)N;
    int* cursor = (int*)(ws + off); off += (size_t)N;

    struct Conv {
        const float *xs, *xt, *Wl, *Wr, *att;
        const int* edge;
    };
    Conv convs[3] = {
        {x_lnc, x_lnc, Wl_ll, Wr_ll, att_ll, edge_ll},
        {x_mi,  x_mi,  Wl_mm, Wr_mm, att_mm, edge_mm},
        {x_lnc, x_mi,  Wl_lm, Wr_lm, att_lm, edge_lm},
    };

    const int gemm_grid = (N + 31) / 32;
    const int egrid     = (E + 255) / 256;
    const int ngrid     = (N + 255) / 256;
    const int node_grid = (N + 3) / 4;

    for (int c = 0; c < 3; ++c) {
        const Conv& cv = convs[c];
        // CSR build
        zero_int<<<ngrid, 256, 0, stream>>>(counts, N);
        hist_tgt<<<egrid, 256, 0, stream>>>(cv.edge + E, counts, E);
        scan_counts<<<1, 1024, 0, stream>>>(counts, base, cursor, N);
        scatter_edges<<<egrid, 256, 0, stream>>>(cv.edge, cv.edge + E, cursor, perm, E);
        // projections
        if (c < 2) {
            gemm256x128_t<2><<<gemm_grid, 256, 0, stream>>>(cv.xs, cv.Wl, cv.Wr,
                                                            xl, xr, N);
        } else {
            gemm256x128_t<1><<<gemm_grid, 256, 0, stream>>>(cv.xs, cv.Wl, nullptr,
                                                            xl, nullptr, N);
            gemm256x128_t<1><<<gemm_grid, 256, 0, stream>>>(cv.xt, cv.Wr, nullptr,
                                                            xr, nullptr, N);
        }
        // fused softmax + aggregation
        if (c == 0)
            node_gatv2<0><<<node_grid, 256, 0, stream>>>(xl, xr, att_ll, base, counts,
                                                         perm, h_l, N);
        else if (c == 1)
            node_gatv2<1><<<node_grid, 256, 0, stream>>>(xl, xr, att_mm, base, counts,
                                                         perm, h_m, N);
        else
            node_gatv2<2><<<node_grid, 256, 0, stream>>>(xl, xr, att_lm, base, counts,
                                                         perm, h_m, N);
    }

    mlp_pairs<<<(P + 31) / 32, 256, 0, stream>>>(h_l, h_m, pairs, P,
                                                 b_ll, b_mm, b_lm,
                                                 gate_W, gate_b, c1_W, c1_b,
                                                 c2_W, c2_b, c3_W, c3_b,
                                                 (float*)d_out);
}

// Round 5
// 874.790 us; speedup vs baseline: 3.7676x; 1.2501x over previous
//
#include <hip/hip_runtime.h>
#include <cmath>

#define NEG_SLOPE 0.2f

typedef __attribute__((ext_vector_type(4))) float f32x4;
typedef __attribute__((ext_vector_type(8))) short s16x8;

__device__ inline unsigned short bf16rn(float x) {
    unsigned int u = __float_as_uint(x);
    u += 0x7fffu + ((u >> 16) & 1u);
    return (unsigned short)(u >> 16);
}
__device__ inline float bf16tof(unsigned short h) {
    return __uint_as_float(((unsigned int)h) << 16);
}

__device__ inline void fma4(float acc[4], const float4 a, const float4 w0,
                            const float4 w1, const float4 w2, const float4 w3) {
    acc[0] += a.x*w0.x + a.y*w1.x + a.z*w2.x + a.w*w3.x;
    acc[1] += a.x*w0.y + a.y*w1.y + a.z*w2.y + a.w*w3.y;
    acc[2] += a.x*w0.z + a.y*w1.z + a.z*w2.z + a.w*w3.z;
    acc[3] += a.x*w0.w + a.y*w1.w + a.z*w2.w + a.w*w3.w;
}

// ---------------------------------------------------------------- prologue kernels
// split gate_W[256][128] fp32 -> fragment-major bf16 hi/lo planes.
// slot: [(nt*8 + kt)*64 + lane]*8 + j  holds W[kt*32 + (lane>>4)*8 + j][nt*16 + (lane&15)]
__global__ __launch_bounds__(256) void split_gateW(const float* __restrict__ W,
                                                   unsigned short* __restrict__ whi,
                                                   unsigned short* __restrict__ wlo) {
    int tid = blockIdx.x * 256 + threadIdx.x;      // 4096 lane-slots
    int nt = tid >> 9, kt = (tid >> 6) & 7, l = tid & 63;
    int col   = nt * 16 + (l & 15);
    int kbase = kt * 32 + (l >> 4) * 8;
#pragma unroll
    for (int j = 0; j < 8; ++j) {
        float x = W[(kbase + j) * 128 + col];
        unsigned short hi = bf16rn(x);
        unsigned short lo = bf16rn(x - bf16tof(hi));
        whi[tid * 8 + j] = hi;
        wlo[tid * 8 + j] = lo;
    }
}

// bconst[j] = [b_ll | 0.5(b_mm+b_lm)] @ gate_W + gate_b
__global__ __launch_bounds__(128) void bconst_k(const float* __restrict__ W,
                                                const float* __restrict__ gate_b,
                                                const float* __restrict__ b_ll,
                                                const float* __restrict__ b_mm,
                                                const float* __restrict__ b_lm,
                                                float* __restrict__ bconst) {
    int j = threadIdx.x;
    float s = gate_b[j];
    for (int k = 0; k < 128; ++k) s += b_ll[k] * W[k * 128 + j];
    for (int k = 0; k < 128; ++k)
        s += 0.5f * (b_mm[k] + b_lm[k]) * W[(128 + k) * 128 + j];
    bconst[j] = s;
}

// ---------------------------------------------------------------- CSR build (batched)
__global__ __launch_bounds__(256) void zero_int(int* p, int n) {
    int i = blockIdx.x * 256 + threadIdx.x;
    if (i < n) p[i] = 0;
}

__global__ __launch_bounds__(256) void hist3(const int* __restrict__ e0,
                                             const int* __restrict__ e1,
                                             const int* __restrict__ e2,
                                             int* __restrict__ counts3, int E, int N) {
    int c = blockIdx.y;
    const int* et = (c == 0 ? e0 : c == 1 ? e1 : e2) + E;   // etgt half
    int e = blockIdx.x * 256 + threadIdx.x;
    if (e < E) atomicAdd(&counts3[c * N + et[e]], 1);
}

// 3 blocks; block c scans conv c's counts -> base, cursor
__global__ __launch_bounds__(1024) void scan3(const int* __restrict__ counts3,
                                              int* __restrict__ base3,
                                              int* __restrict__ cursor3, int n) {
    __shared__ int tot[1024];
    const int c = blockIdx.x;
    const int* counts = counts3 + c * n;
    int* base   = base3 + c * n;
    int* cursor = cursor3 + c * n;
    const int t = threadIdx.x;
    const int chunk = (n + 1023) >> 10;
    const int i0 = t * chunk;
    int s = 0;
    for (int i = 0; i < chunk; ++i) {
        int idx = i0 + i;
        if (idx < n) s += counts[idx];
    }
    tot[t] = s;
    __syncthreads();
    for (int d = 1; d < 1024; d <<= 1) {
        int v = (t >= d) ? tot[t - d] : 0;
        __syncthreads();
        tot[t] += v;
        __syncthreads();
    }
    int run = (t == 0) ? 0 : tot[t - 1];
    for (int i = 0; i < chunk; ++i) {
        int idx = i0 + i;
        if (idx < n) {
            base[idx]   = run;
            cursor[idx] = run;
            run += counts[idx];
        }
    }
}

__global__ __launch_bounds__(256) void scatter_edges(const int* __restrict__ esrc,
                                                     const int* __restrict__ etgt,
                                                     int* __restrict__ cursor,
                                                     int* __restrict__ perm, int E) {
    int e = blockIdx.x * 256 + threadIdx.x;
    if (e >= E) return;
    int pos = atomicAdd(&cursor[etgt[e]], 1);
    perm[pos] = esrc[e];
}

// ---------------------------------------------------------------- projection GEMMs (fp32)
template <int NW>
__global__ __launch_bounds__(256) void gemm256x128_t(const float* __restrict__ A,
                                                     const float* __restrict__ W1,
                                                     const float* __restrict__ W2,
                                                     float* __restrict__ C1,
                                                     float* __restrict__ C2, int M) {
    __shared__ float At[32][256];
    const int t  = threadIdx.x;
    const int m0 = blockIdx.x * 32;

#pragma unroll
    for (int i = 0; i < 8; ++i) {
        int q   = t + i * 256;
        int row = q >> 6;
        int col = (q & 63) << 2;
        float4 v = {0.f, 0.f, 0.f, 0.f};
        if (m0 + row < M) v = *(const float4*)&A[(size_t)(m0 + row) * 256 + col];
        *(float4*)&At[row][col] = v;
    }
    __syncthreads();

    const int p0 = (t >> 5) * 4;
    const int n0 = (t & 31) * 4;

#pragma unroll
    for (int ph = 0; ph < NW; ++ph) {
        const float* __restrict__ W = ph ? W2 : W1;
        float* __restrict__ C       = ph ? C2 : C1;
        float acc[4][4] = {};
#pragma unroll 2
        for (int k0 = 0; k0 < 256; k0 += 4) {
            float4 a0 = *(const float4*)&At[p0 + 0][k0];
            float4 a1 = *(const float4*)&At[p0 + 1][k0];
            float4 a2 = *(const float4*)&At[p0 + 2][k0];
            float4 a3 = *(const float4*)&At[p0 + 3][k0];
            float4 w0 = *(const float4*)&W[(k0 + 0) * 128 + n0];
            float4 w1 = *(const float4*)&W[(k0 + 1) * 128 + n0];
            float4 w2 = *(const float4*)&W[(k0 + 2) * 128 + n0];
            float4 w3 = *(const float4*)&W[(k0 + 3) * 128 + n0];
            fma4(acc[0], a0, w0, w1, w2, w3);
            fma4(acc[1], a1, w0, w1, w2, w3);
            fma4(acc[2], a2, w0, w1, w2, w3);
            fma4(acc[3], a3, w0, w1, w2, w3);
        }
#pragma unroll
        for (int i = 0; i < 4; ++i) {
            int row = m0 + p0 + i;
            if (row < M) {
                float4 v = {acc[i][0], acc[i][1], acc[i][2], acc[i][3]};
                *(float4*)&C[(size_t)row * 128 + n0] = v;
            }
        }
    }
}

// ---------------------------------------------------------------- fused per-node GATv2
// One wave per target; online softmax; h written as bf16 hi/lo planes.
// MODE 0: h = agg ; MODE 1: h = 0.5*agg ; MODE 2: h += 0.5*agg
#define LEAKY(z) ((z) > 0.f ? (z) : NEG_SLOPE * (z))
#define WREDUCE(p) { p += __shfl_xor(p, 1); p += __shfl_xor(p, 2); \
                     p += __shfl_xor(p, 4); p += __shfl_xor(p, 8); \
                     p += __shfl_xor(p, 16); }

template <int MODE>
__global__ __launch_bounds__(256) void node_gatv2(const float* __restrict__ xl,
                                                  const float* __restrict__ xr,
                                                  const float* __restrict__ att,
                                                  const int* __restrict__ base,
                                                  const int* __restrict__ counts,
                                                  const int* __restrict__ perm,
                                                  unsigned short* __restrict__ hhi,
                                                  unsigned short* __restrict__ hlo,
                                                  int N) {
    const int node = blockIdx.x * 4 + (threadIdx.x >> 6);
    if (node >= N) return;
    const int l = threadIdx.x & 63;

    const float2 xrv  = *(const float2*)&xr[(size_t)node * 128 + l * 2];
    const float2 attv = *(const float2*)&att[l * 2];
    const int b   = base[node];
    const int deg = counts[node];

    float  m   = -INFINITY;
    float  den = 0.0f;
    float2 acc = {0.0f, 0.0f};

    int k = 0;
    for (; k + 3 < deg; k += 4) {
        int s0 = perm[b + k + 0];
        int s1 = perm[b + k + 1];
        int s2 = perm[b + k + 2];
        int s3 = perm[b + k + 3];
        float2 x0 = *(const float2*)&xl[(size_t)s0 * 128 + l * 2];
        float2 x1 = *(const float2*)&xl[(size_t)s1 * 128 + l * 2];
        float2 x2 = *(const float2*)&xl[(size_t)s2 * 128 + l * 2];
        float2 x3 = *(const float2*)&xl[(size_t)s3 * 128 + l * 2];

        float p0 = LEAKY(x0.x + xrv.x) * attv.x + LEAKY(x0.y + xrv.y) * attv.y;
        float p1 = LEAKY(x1.x + xrv.x) * attv.x + LEAKY(x1.y + xrv.y) * attv.y;
        float p2 = LEAKY(x2.x + xrv.x) * attv.x + LEAKY(x2.y + xrv.y) * attv.y;
        float p3 = LEAKY(x3.x + xrv.x) * attv.x + LEAKY(x3.y + xrv.y) * attv.y;
        WREDUCE(p0) WREDUCE(p1) WREDUCE(p2) WREDUCE(p3)

        float mn = fmaxf(fmaxf(fmaxf(m, p0), fmaxf(p1, p2)), p3);
        float f  = expf(m  - mn);
        float e0 = expf(p0 - mn);
        float e1 = expf(p1 - mn);
        float e2 = expf(p2 - mn);
        float e3 = expf(p3 - mn);
        den   = den   * f + e0 + e1 + e2 + e3;
        acc.x = acc.x * f + e0 * x0.x + e1 * x1.x + e2 * x2.x + e3 * x3.x;
        acc.y = acc.y * f + e0 * x0.y + e1 * x1.y + e2 * x2.y + e3 * x3.y;
        m = mn;
    }
    for (; k < deg; ++k) {
        int src = perm[b + k];
        float2 x = *(const float2*)&xl[(size_t)src * 128 + l * 2];
        float p = LEAKY(x.x + xrv.x) * attv.x + LEAKY(x.y + xrv.y) * attv.y;
        WREDUCE(p)
        float mn = fmaxf(m, p);
        float f  = expf(m - mn);
        float ex = expf(p - mn);
        den   = den   * f + ex;
        acc.x = acc.x * f + ex * x.x;
        acc.y = acc.y * f + ex * x.y;
        m = mn;
    }

    const float scale = (MODE == 0) ? 1.0f : 0.5f;
    const float r = scale / fmaxf(den, 1e-16f);
    float ox = acc.x * r, oy = acc.y * r;

    const size_t idx = (size_t)node * 128 + l * 2;
    if (MODE == 2) {
        ushort2 ph = *(const ushort2*)&hhi[idx];
        ushort2 pl = *(const ushort2*)&hlo[idx];
        ox += bf16tof(ph.x) + bf16tof(pl.x);
        oy += bf16tof(ph.y) + bf16tof(pl.y);
    }
    unsigned short hx = bf16rn(ox);
    unsigned short lx = bf16rn(ox - bf16tof(hx));
    unsigned short hy = bf16rn(oy);
    unsigned short ly = bf16rn(oy - bf16tof(hy));
    ushort2 vh; vh.x = hx; vh.y = hy;
    ushort2 vl; vl.x = lx; vl.y = ly;
    *(ushort2*)&hhi[idx] = vh;
    *(ushort2*)&hlo[idx] = vl;
}

// ---------------------------------------------------------------- pair MLP (MFMA gate)
// 64 pairs/block, 256 threads (4 waves x 16 pairs).
__global__ __launch_bounds__(256) void mlp_fused(
        const unsigned short* __restrict__ hlhi, const unsigned short* __restrict__ hllo,
        const unsigned short* __restrict__ hmhi, const unsigned short* __restrict__ hmlo,
        const int* __restrict__ pairs, int P,
        const unsigned short* __restrict__ whi, const unsigned short* __restrict__ wlo,
        const float* __restrict__ bconst,
        const float* __restrict__ b_ll, const float* __restrict__ b_mm,
        const float* __restrict__ b_lm,
        const float* __restrict__ c1_W, const float* __restrict__ c1_b,
        const float* __restrict__ c2_W, const float* __restrict__ c2_b,
        const float* __restrict__ c3_W, const float* __restrict__ c3_b,
        float* __restrict__ out) {
    __shared__ float fus[64][132];
    __shared__ float h1s[64][68];
    const int t  = threadIdx.x;
    const int pb = blockIdx.x * 64;

    // ---- gate GEMM via MFMA bf16 hi/lo split: [64,256]@[256,128] ----
    {
        const int w = t >> 6, l = t & 63;
        const int lg = l >> 4, lr = l & 15;
        int pidx = pb + w * 16 + lr; if (pidx >= P) pidx = P - 1;
        const int r1 = pairs[pidx * 2 + 0];
        const int r2 = pairs[pidx * 2 + 1];

        f32x4 acc[8];
#pragma unroll
        for (int nt = 0; nt < 8; ++nt) acc[nt] = (f32x4){0.f, 0.f, 0.f, 0.f};

#pragma unroll
        for (int kt = 0; kt < 8; ++kt) {
            const unsigned short* Ahi = (kt < 4) ? hlhi : hmhi;
            const unsigned short* Alo = (kt < 4) ? hllo : hmlo;
            const int arow  = (kt < 4) ? r1 : r2;
            const int kbase = (kt & 3) * 32 + lg * 8;
            s16x8 ahi = *(const s16x8*)&Ahi[(size_t)arow * 128 + kbase];
            s16x8 alo = *(const s16x8*)&Alo[(size_t)arow * 128 + kbase];
#pragma unroll
            for (int nt = 0; nt < 8; ++nt) {
                const int boff = ((nt * 8 + kt) * 64 + l) * 8;
                s16x8 bhi = *(const s16x8*)&whi[boff];
                s16x8 blo = *(const s16x8*)&wlo[boff];
                acc[nt] = __builtin_amdgcn_mfma_f32_16x16x32_bf16(alo, bhi, acc[nt], 0, 0, 0);
                acc[nt] = __builtin_amdgcn_mfma_f32_16x16x32_bf16(ahi, blo, acc[nt], 0, 0, 0);
                acc[nt] = __builtin_amdgcn_mfma_f32_16x16x32_bf16(ahi, bhi, acc[nt], 0, 0, 0);
            }
        }
        // g -> LDS  (D: col = lane&15, row = (lane>>4)*4 + reg)
#pragma unroll
        for (int nt = 0; nt < 8; ++nt) {
            const int col = nt * 16 + lr;
#pragma unroll
            for (int r = 0; r < 4; ++r) {
                const int row = w * 16 + lg * 4 + r;
                float x  = acc[nt][r] + bconst[col];
                float rl = fmaxf(x, 0.0f);
                fus[row][col] = 1.0f / (1.0f + expf(-rl));
            }
        }
    }
    __syncthreads();

    // ---- fuse: fused = g*(f1+b1) + (1-g)*(f2+bm), in-place into fus ----
    {
        const int p  = t >> 2;
        const int cb = (t & 3) * 32;
        int pidx = pb + p; if (pidx >= P) pidx = P - 1;
        const int r1 = pairs[pidx * 2 + 0];
        const int r2 = pairs[pidx * 2 + 1];
#pragma unroll
        for (int jj = 0; jj < 4; ++jj) {
            const int c = cb + jj * 8;
            s16x8 a1h = *(const s16x8*)&hlhi[(size_t)r1 * 128 + c];
            s16x8 a1l = *(const s16x8*)&hllo[(size_t)r1 * 128 + c];
            s16x8 a2h = *(const s16x8*)&hmhi[(size_t)r2 * 128 + c];
            s16x8 a2l = *(const s16x8*)&hmlo[(size_t)r2 * 128 + c];
            float fo[8];
#pragma unroll
            for (int q = 0; q < 8; ++q) {
                float g  = fus[p][c + q];
                float v1 = bf16tof((unsigned short)a1h[q]) + bf16tof((unsigned short)a1l[q])
                         + b_ll[c + q];
                float v2 = bf16tof((unsigned short)a2h[q]) + bf16tof((unsigned short)a2l[q])
                         + 0.5f * (b_mm[c + q] + b_lm[c + q]);
                fo[q] = g * v1 + (1.0f - g) * v2;
            }
            float4 w0 = {fo[0], fo[1], fo[2], fo[3]};
            float4 w1 = {fo[4], fo[5], fo[6], fo[7]};
            *(float4*)&fus[p][c + 0] = w0;
            *(float4*)&fus[p][c + 4] = w1;
        }
    }
    __syncthreads();

    // ---- c1: [64,128]@[128,64] -> relu -> h1s ----
    {
        const int p0 = (t >> 4) * 4;
        const int o0 = (t & 15) * 4;
        float acc[4][4] = {};
#pragma unroll 2
        for (int k0 = 0; k0 < 128; k0 += 4) {
            float4 a0 = *(const float4*)&fus[p0 + 0][k0];
            float4 a1 = *(const float4*)&fus[p0 + 1][k0];
            float4 a2 = *(const float4*)&fus[p0 + 2][k0];
            float4 a3 = *(const float4*)&fus[p0 + 3][k0];
            float4 w0 = *(const float4*)&c1_W[(k0 + 0) * 64 + o0];
            float4 w1 = *(const float4*)&c1_W[(k0 + 1) * 64 + o0];
            float4 w2 = *(const float4*)&c1_W[(k0 + 2) * 64 + o0];
            float4 w3 = *(const float4*)&c1_W[(k0 + 3) * 64 + o0];
            fma4(acc[0], a0, w0, w1, w2, w3);
            fma4(acc[1], a1, w0, w1, w2, w3);
            fma4(acc[2], a2, w0, w1, w2, w3);
            fma4(acc[3], a3, w0, w1, w2, w3);
        }
#pragma unroll
        for (int i = 0; i < 4; ++i)
#pragma unroll
            for (int n = 0; n < 4; ++n)
                h1s[p0 + i][o0 + n] = fmaxf(acc[i][n] + c1_b[o0 + n], 0.0f);
    }
    __syncthreads();

    // ---- c2: [64,64]@[64,32] -> relu -> h2 (overlays fus region, stride 36) ----
    float* h2 = &fus[0][0];
    {
        const int p0 = (t >> 3) * 2;
        const int o0 = (t & 7) * 4;
        float acc[2][4] = {};
#pragma unroll
        for (int k0 = 0; k0 < 64; k0 += 4) {
            float4 a0 = *(const float4*)&h1s[p0 + 0][k0];
            float4 a1 = *(const float4*)&h1s[p0 + 1][k0];
            float4 w0 = *(const float4*)&c2_W[(k0 + 0) * 32 + o0];
            float4 w1 = *(const float4*)&c2_W[(k0 + 1) * 32 + o0];
            float4 w2 = *(const float4*)&c2_W[(k0 + 2) * 32 + o0];
            float4 w3 = *(const float4*)&c2_W[(k0 + 3) * 32 + o0];
            fma4(acc[0], a0, w0, w1, w2, w3);
            fma4(acc[1], a1, w0, w1, w2, w3);
        }
        __syncthreads();   // all fus reads (c1 phase) done before overwrite
#pragma unroll
        for (int i = 0; i < 2; ++i)
#pragma unroll
            for (int n = 0; n < 4; ++n)
                h2[(p0 + i) * 36 + o0 + n] = fmaxf(acc[i][n] + c2_b[o0 + n], 0.0f);
    }
    __syncthreads();

    // ---- c3: [64,32]@[32,1] ----
    if (t < 64) {
        int pi = pb + t;
        if (pi < P) {
            float s = c3_b[0];
#pragma unroll
            for (int k = 0; k < 32; ++k) s += h2[t * 36 + k] * c3_W[k];
            out[pi] = s;
        }
    }
}

// ---------------------------------------------------------------- launch
extern "C" void kernel_launch(void* const* d_in, const int* in_sizes, int n_in,
                              void* d_out, int out_size, void* d_ws, size_t ws_size,
                              hipStream_t stream) {
    const float* x_lnc  = (const float*)d_in[0];
    const float* x_mi   = (const float*)d_in[1];
    const float* Wl_ll  = (const float*)d_in[2];
    const float* Wr_ll  = (const float*)d_in[3];
    const float* att_ll = (const float*)d_in[4];
    const float* b_ll   = (const float*)d_in[5];
    const float* Wl_mm  = (const float*)d_in[6];
    const float* Wr_mm  = (const float*)d_in[7];
    const float* att_mm = (const float*)d_in[8];
    const float* b_mm   = (const float*)d_in[9];
    const float* Wl_lm  = (const float*)d_in[10];
    const float* Wr_lm  = (const float*)d_in[11];
    const float* att_lm = (const float*)d_in[12];
    const float* b_lm   = (const float*)d_in[13];
    const float* gate_W = (const float*)d_in[14];
    const float* gate_b = (const float*)d_in[15];
    const float* c1_W   = (const float*)d_in[16];
    const float* c1_b   = (const float*)d_in[17];
    const float* c2_W   = (const float*)d_in[18];
    const float* c2_b   = (const float*)d_in[19];
    const float* c3_W   = (const float*)d_in[20];
    const float* c3_b   = (const float*)d_in[21];
    const int* edge_ll  = (const int*)d_in[22];
    const int* edge_mm  = (const int*)d_in[23];
    const int* edge_lm  = (const int*)d_in[24];
    const int* pairs    = (const int*)d_in[25];

    const int N = in_sizes[0] / 256;    // 30000
    const int E = in_sizes[22] / 2;     // 480000
    const int P = in_sizes[25] / 2;     // 100000

    char* ws = (char*)d_ws;
    size_t o = 0;
    auto alloc = [&](size_t bytes) { char* p = ws + o; o += (bytes + 255) & ~(size_t)255; return p; };

    float* xl            = (float*)alloc((size_t)N * 128 * 4);
    float* xr            = (float*)alloc((size_t)N * 128 * 4);
    unsigned short* hlhi = (unsigned short*)alloc((size_t)N * 128 * 2);
    unsigned short* hllo = (unsigned short*)alloc((size_t)N * 128 * 2);
    unsigned short* hmhi = (unsigned short*)alloc((size_t)N * 128 * 2);
    unsigned short* hmlo = (unsigned short*)alloc((size_t)N * 128 * 2);
    int* perm            = (int*)alloc((size_t)E * 4);
    int* counts3         = (int*)alloc((size_t)3 * N * 4);
    int* base3           = (int*)alloc((size_t)3 * N * 4);
    int* cursor3         = (int*)alloc((size_t)3 * N * 4);
    unsigned short* whi  = (unsigned short*)alloc(256 * 128 * 2);
    unsigned short* wlo  = (unsigned short*)alloc(256 * 128 * 2);
    float* bconst        = (float*)alloc(128 * 4);

    const int egrid     = (E + 255) / 256;
    const int gemm_grid = (N + 31) / 32;
    const int node_grid = (N + 3) / 4;

    // prologue: gate-W split + bias const + batched CSR front half
    split_gateW<<<16, 256, 0, stream>>>(gate_W, whi, wlo);
    bconst_k<<<1, 128, 0, stream>>>(gate_W, gate_b, b_ll, b_mm, b_lm, bconst);
    zero_int<<<(3 * N + 255) / 256, 256, 0, stream>>>(counts3, 3 * N);
    hist3<<<dim3(egrid, 3), 256, 0, stream>>>(edge_ll, edge_mm, edge_lm, counts3, E, N);
    scan3<<<3, 1024, 0, stream>>>(counts3, base3, cursor3, N);

    struct Conv {
        const float *xs, *xt, *Wl, *Wr, *att;
        const int* edge;
    };
    Conv convs[3] = {
        {x_lnc, x_lnc, Wl_ll, Wr_ll, att_ll, edge_ll},
        {x_mi,  x_mi,  Wl_mm, Wr_mm, att_mm, edge_mm},
        {x_lnc, x_mi,  Wl_lm, Wr_lm, att_lm, edge_lm},
    };

    for (int c = 0; c < 3; ++c) {
        const Conv& cv = convs[c];
        scatter_edges<<<egrid, 256, 0, stream>>>(cv.edge, cv.edge + E,
                                                 cursor3 + c * N, perm, E);
        if (c < 2) {
            gemm256x128_t<2><<<gemm_grid, 256, 0, stream>>>(cv.xs, cv.Wl, cv.Wr,
                                                            xl, xr, N);
        } else {
            gemm256x128_t<1><<<gemm_grid, 256, 0, stream>>>(cv.xs, cv.Wl, nullptr,
                                                            xl, nullptr, N);
            gemm256x128_t<1><<<gemm_grid, 256, 0, stream>>>(cv.xt, cv.Wr, nullptr,
                                                            xr, nullptr, N);
        }
        if (c == 0)
            node_gatv2<0><<<node_grid, 256, 0, stream>>>(xl, xr, att_ll, base3,
                                                         counts3, perm, hlhi, hllo, N);
        else if (c == 1)
            node_gatv2<1><<<node_grid, 256, 0, stream>>>(xl, xr, att_mm, base3 + N,
                                                         counts3 + N, perm, hmhi, hmlo, N);
        else
            node_gatv2<2><<<node_grid, 256, 0, stream>>>(xl, xr, att_lm, base3 + 2 * N,
                                                         counts3 + 2 * N, perm, hmhi, hmlo, N);
    }

    mlp_fused<<<(P + 63) / 64, 256, 0, stream>>>(hlhi, hllo, hmhi, hmlo, pairs, P,
                                                 whi, wlo, bconst,
                                                 b_ll, b_mm, b_lm,
                                                 c1_W, c1_b, c2_W, c2_b, c3_W, c3_b,
                                                 (float*)d_out);
}

// Round 9
// 700.862 us; speedup vs baseline: 4.7026x; 1.2482x over previous
//
#include <hip/hip_runtime.h>
#include <cmath>

#define NEG_SLOPE 0.2f

typedef __attribute__((ext_vector_type(4))) float f32x4;
typedef __attribute__((ext_vector_type(8))) short s16x8;

__device__ inline unsigned short bf16rn(float x) {
    unsigned int u = __float_as_uint(x);
    u += 0x7fffu + ((u >> 16) & 1u);
    return (unsigned short)(u >> 16);
}
__device__ inline float bf16tof(unsigned short h) {
    return __uint_as_float(((unsigned int)h) << 16);
}

__device__ inline void fma4(float acc[4], const float4 a, const float4 w0,
                            const float4 w1, const float4 w2, const float4 w3) {
    acc[0] += a.x*w0.x + a.y*w1.x + a.z*w2.x + a.w*w3.x;
    acc[1] += a.x*w0.y + a.y*w1.y + a.z*w2.y + a.w*w3.y;
    acc[2] += a.x*w0.z + a.y*w1.z + a.z*w2.z + a.w*w3.z;
    acc[3] += a.x*w0.w + a.y*w1.w + a.z*w2.w + a.w*w3.w;
}

// ---------------------------------------------------------------- weight split (batched, 7 weights)
// Each W is [256][128] fp32 -> fragment-major bf16 hi/lo planes (32768 shorts each).
// slot tid = (nt*8 + kt)*64 + lane ; element j: W[kt*32 + (lane>>4)*8 + j][nt*16 + (lane&15)]
__global__ __launch_bounds__(256) void split_w7(const float* __restrict__ w0,
                                                const float* __restrict__ w1,
                                                const float* __restrict__ w2,
                                                const float* __restrict__ w3,
                                                const float* __restrict__ w4,
                                                const float* __restrict__ w5,
                                                const float* __restrict__ w6,
                                                unsigned short* __restrict__ whi,
                                                unsigned short* __restrict__ wlo) {
    const int widx = blockIdx.y;
    const float* W = widx == 0 ? w0 : widx == 1 ? w1 : widx == 2 ? w2 :
                     widx == 3 ? w3 : widx == 4 ? w4 : widx == 5 ? w5 : w6;
    int tid = blockIdx.x * 256 + threadIdx.x;      // 0..4095
    int nt = tid >> 9, kt = (tid >> 6) & 7, l = tid & 63;
    int col   = nt * 16 + (l & 15);
    int kbase = kt * 32 + (l >> 4) * 8;
    size_t base = (size_t)widx * 32768 + (size_t)tid * 8;
#pragma unroll
    for (int j = 0; j < 8; ++j) {
        float x = W[(kbase + j) * 128 + col];
        unsigned short hi = bf16rn(x);
        unsigned short lo = bf16rn(x - bf16tof(hi));
        whi[base + j] = hi;
        wlo[base + j] = lo;
    }
}

// bconst[j] = [b_ll | 0.5(b_mm+b_lm)] @ gate_W + gate_b
__global__ __launch_bounds__(128) void bconst_k(const float* __restrict__ W,
                                                const float* __restrict__ gate_b,
                                                const float* __restrict__ b_ll,
                                                const float* __restrict__ b_mm,
                                                const float* __restrict__ b_lm,
                                                float* __restrict__ bconst) {
    int j = threadIdx.x;
    float s = gate_b[j];
    for (int k = 0; k < 128; ++k) s += b_ll[k] * W[k * 128 + j];
    for (int k = 0; k < 128; ++k)
        s += 0.5f * (b_mm[k] + b_lm[k]) * W[(128 + k) * 128 + j];
    bconst[j] = s;
}

// ---------------------------------------------------------------- CSR build (batched)
__global__ __launch_bounds__(256) void zero_int(int* p, int n) {
    int i = blockIdx.x * 256 + threadIdx.x;
    if (i < n) p[i] = 0;
}

__global__ __launch_bounds__(256) void hist3(const int* __restrict__ e0,
                                             const int* __restrict__ e1,
                                             const int* __restrict__ e2,
                                             int* __restrict__ counts3, int E, int N) {
    int c = blockIdx.y;
    const int* et = (c == 0 ? e0 : c == 1 ? e1 : e2) + E;
    int e = blockIdx.x * 256 + threadIdx.x;
    if (e < E) atomicAdd(&counts3[c * N + et[e]], 1);
}

__global__ __launch_bounds__(1024) void scan3(const int* __restrict__ counts3,
                                              int* __restrict__ base3,
                                              int* __restrict__ cursor3, int n) {
    __shared__ int tot[1024];
    const int c = blockIdx.x;
    const int* counts = counts3 + c * n;
    int* base   = base3 + c * n;
    int* cursor = cursor3 + c * n;
    const int t = threadIdx.x;
    const int chunk = (n + 1023) >> 10;
    const int i0 = t * chunk;
    int s = 0;
    for (int i = 0; i < chunk; ++i) {
        int idx = i0 + i;
        if (idx < n) s += counts[idx];
    }
    tot[t] = s;
    __syncthreads();
    for (int d = 1; d < 1024; d <<= 1) {
        int v = (t >= d) ? tot[t - d] : 0;
        __syncthreads();
        tot[t] += v;
        __syncthreads();
    }
    int run = (t == 0) ? 0 : tot[t - 1];
    for (int i = 0; i < chunk; ++i) {
        int idx = i0 + i;
        if (idx < n) {
            base[idx]   = run;
            cursor[idx] = run;
            run += counts[idx];
        }
    }
}

__global__ __launch_bounds__(256) void scatter_edges(const int* __restrict__ esrc,
                                                     const int* __restrict__ etgt,
                                                     int* __restrict__ cursor,
                                                     int* __restrict__ perm, int E) {
    int e = blockIdx.x * 256 + threadIdx.x;
    if (e >= E) return;
    int pos = atomicAdd(&cursor[etgt[e]], 1);
    perm[pos] = esrc[e];
}

// ---------------------------------------------------------------- MFMA projection GEMM
// C[M][128] = A[M][256] @ W[256][128] via bf16 hi/lo split (3 MFMAs / k-tile).
// Block = 4 waves, 64 rows; wave w owns rows m0 + w*16 + (lane&15).
// A fragments converted in-register (no LDS); W prepacked fragment-major.
// NW=2 reuses the A fragments for a second weight/output.
template <int NW>
__global__ __launch_bounds__(256) void gemm_mfma(const float* __restrict__ A,
                                                 const unsigned short* __restrict__ w1hi,
                                                 const unsigned short* __restrict__ w1lo,
                                                 const unsigned short* __restrict__ w2hi,
                                                 const unsigned short* __restrict__ w2lo,
                                                 float* __restrict__ C1,
                                                 float* __restrict__ C2, int M) {
    const int t = threadIdx.x;
    const int w = t >> 6, l = t & 63;
    const int lg = l >> 4, lr = l & 15;
    const int row  = blockIdx.x * 64 + w * 16 + lr;
    const int arow = row < M ? row : M - 1;

    s16x8 ahi[8], alo[8];
#pragma unroll
    for (int kt = 0; kt < 8; ++kt) {
        const float* ap = &A[(size_t)arow * 256 + kt * 32 + lg * 8];
        float4 f0 = *(const float4*)ap;
        float4 f1 = *(const float4*)(ap + 4);
        float xs[8] = {f0.x, f0.y, f0.z, f0.w, f1.x, f1.y, f1.z, f1.w};
        s16x8 h, lo;
#pragma unroll
        for (int j = 0; j < 8; ++j) {
            unsigned short hh = bf16rn(xs[j]);
            h[j]  = (short)hh;
            lo[j] = (short)bf16rn(xs[j] - bf16tof(hh));
        }
        ahi[kt] = h;
        alo[kt] = lo;
    }

    const int orow0 = blockIdx.x * 64 + w * 16 + lg * 4;
#pragma unroll
    for (int ph = 0; ph < NW; ++ph) {
        const unsigned short* whi = ph ? w2hi : w1hi;
        const unsigned short* wlo = ph ? w2lo : w1lo;
        float* __restrict__ C     = ph ? C2 : C1;
        f32x4 acc[8];
#pragma unroll
        for (int nt = 0; nt < 8; ++nt) acc[nt] = (f32x4){0.f, 0.f, 0.f, 0.f};
#pragma unroll
        for (int kt = 0; kt < 8; ++kt) {
#pragma unroll
            for (int nt = 0; nt < 8; ++nt) {
                const int boff = ((nt * 8 + kt) * 64 + l) * 8;
                s16x8 bhi = *(const s16x8*)&whi[boff];
                s16x8 blo = *(const s16x8*)&wlo[boff];
                acc[nt] = __builtin_amdgcn_mfma_f32_16x16x32_bf16(alo[kt], bhi, acc[nt], 0, 0, 0);
                acc[nt] = __builtin_amdgcn_mfma_f32_16x16x32_bf16(ahi[kt], blo, acc[nt], 0, 0, 0);
                acc[nt] = __builtin_amdgcn_mfma_f32_16x16x32_bf16(ahi[kt], bhi, acc[nt], 0, 0, 0);
            }
        }
#pragma unroll
        for (int nt = 0; nt < 8; ++nt) {
#pragma unroll
            for (int r = 0; r < 4; ++r) {
                int orow = orow0 + r;
                if (orow < M) C[(size_t)orow * 128 + nt * 16 + lr] = acc[nt][r];
            }
        }
    }
}

// two independent single-output GEMMs in one launch (blockIdx.y selects)
__global__ __launch_bounds__(256) void gemm_mfma_pair(const float* __restrict__ A0,
                                                      const float* __restrict__ A1,
                                                      const unsigned short* __restrict__ wahi,
                                                      const unsigned short* __restrict__ walo,
                                                      const unsigned short* __restrict__ wbhi,
                                                      const unsigned short* __restrict__ wblo,
                                                      float* __restrict__ C0,
                                                      float* __restrict__ C1, int M) {
    const int t = threadIdx.x;
    const int w = t >> 6, l = t & 63;
    const int lg = l >> 4, lr = l & 15;
    const int row  = blockIdx.x * 64 + w * 16 + lr;
    const int arow = row < M ? row : M - 1;
    const float* __restrict__ A = blockIdx.y ? A1 : A0;
    const unsigned short* __restrict__ whi = blockIdx.y ? wbhi : wahi;
    const unsigned short* __restrict__ wlo = blockIdx.y ? wblo : walo;
    float* __restrict__ C = blockIdx.y ? C1 : C0;

    s16x8 ahi[8], alo[8];
#pragma unroll
    for (int kt = 0; kt < 8; ++kt) {
        const float* ap = &A[(size_t)arow * 256 + kt * 32 + lg * 8];
        float4 f0 = *(const float4*)ap;
        float4 f1 = *(const float4*)(ap + 4);
        float xs[8] = {f0.x, f0.y, f0.z, f0.w, f1.x, f1.y, f1.z, f1.w};
        s16x8 h, lo;
#pragma unroll
        for (int j = 0; j < 8; ++j) {
            unsigned short hh = bf16rn(xs[j]);
            h[j]  = (short)hh;
            lo[j] = (short)bf16rn(xs[j] - bf16tof(hh));
        }
        ahi[kt] = h;
        alo[kt] = lo;
    }

    f32x4 acc[8];
#pragma unroll
    for (int nt = 0; nt < 8; ++nt) acc[nt] = (f32x4){0.f, 0.f, 0.f, 0.f};
#pragma unroll
    for (int kt = 0; kt < 8; ++kt) {
#pragma unroll
        for (int nt = 0; nt < 8; ++nt) {
            const int boff = ((nt * 8 + kt) * 64 + l) * 8;
            s16x8 bhi = *(const s16x8*)&whi[boff];
            s16x8 blo = *(const s16x8*)&wlo[boff];
            acc[nt] = __builtin_amdgcn_mfma_f32_16x16x32_bf16(alo[kt], bhi, acc[nt], 0, 0, 0);
            acc[nt] = __builtin_amdgcn_mfma_f32_16x16x32_bf16(ahi[kt], blo, acc[nt], 0, 0, 0);
            acc[nt] = __builtin_amdgcn_mfma_f32_16x16x32_bf16(ahi[kt], bhi, acc[nt], 0, 0, 0);
        }
    }
    const int orow0 = blockIdx.x * 64 + w * 16 + lg * 4;
#pragma unroll
    for (int nt = 0; nt < 8; ++nt) {
#pragma unroll
        for (int r = 0; r < 4; ++r) {
            int orow = orow0 + r;
            if (orow < M) C[(size_t)orow * 128 + nt * 16 + lr] = acc[nt][r];
        }
    }
}

// ---------------------------------------------------------------- fused per-node GATv2
#define LEAKY(z) ((z) > 0.f ? (z) : NEG_SLOPE * (z))
#define WREDUCE(p) { p += __shfl_xor(p, 1); p += __shfl_xor(p, 2); \
                     p += __shfl_xor(p, 4); p += __shfl_xor(p, 8); \
                     p += __shfl_xor(p, 16); }

template <int MODE>
__global__ __launch_bounds__(256) void node_gatv2(const float* __restrict__ xl,
                                                  const float* __restrict__ xr,
                                                  const float* __restrict__ att,
                                                  const int* __restrict__ base,
                                                  const int* __restrict__ counts,
                                                  const int* __restrict__ perm,
                                                  unsigned short* __restrict__ hhi,
                                                  unsigned short* __restrict__ hlo,
                                                  int N) {
    const int node = blockIdx.x * 4 + (threadIdx.x >> 6);
    if (node >= N) return;
    const int l = threadIdx.x & 63;

    const float2 xrv  = *(const float2*)&xr[(size_t)node * 128 + l * 2];
    const float2 attv = *(const float2*)&att[l * 2];
    const int b   = base[node];
    const int deg = counts[node];

    float  m   = -INFINITY;
    float  den = 0.0f;
    float2 acc = {0.0f, 0.0f};

    int k = 0;
    for (; k + 3 < deg; k += 4) {
        int s0 = perm[b + k + 0];
        int s1 = perm[b + k + 1];
        int s2 = perm[b + k + 2];
        int s3 = perm[b + k + 3];
        float2 x0 = *(const float2*)&xl[(size_t)s0 * 128 + l * 2];
        float2 x1 = *(const float2*)&xl[(size_t)s1 * 128 + l * 2];
        float2 x2 = *(const float2*)&xl[(size_t)s2 * 128 + l * 2];
        float2 x3 = *(const float2*)&xl[(size_t)s3 * 128 + l * 2];

        float p0 = LEAKY(x0.x + xrv.x) * attv.x + LEAKY(x0.y + xrv.y) * attv.y;
        float p1 = LEAKY(x1.x + xrv.x) * attv.x + LEAKY(x1.y + xrv.y) * attv.y;
        float p2 = LEAKY(x2.x + xrv.x) * attv.x + LEAKY(x2.y + xrv.y) * attv.y;
        float p3 = LEAKY(x3.x + xrv.x) * attv.x + LEAKY(x3.y + xrv.y) * attv.y;
        WREDUCE(p0) WREDUCE(p1) WREDUCE(p2) WREDUCE(p3)

        float mn = fmaxf(fmaxf(fmaxf(m, p0), fmaxf(p1, p2)), p3);
        float f  = expf(m  - mn);
        float e0 = expf(p0 - mn);
        float e1 = expf(p1 - mn);
        float e2 = expf(p2 - mn);
        float e3 = expf(p3 - mn);
        den   = den   * f + e0 + e1 + e2 + e3;
        acc.x = acc.x * f + e0 * x0.x + e1 * x1.x + e2 * x2.x + e3 * x3.x;
        acc.y = acc.y * f + e0 * x0.y + e1 * x1.y + e2 * x2.y + e3 * x3.y;
        m = mn;
    }
    for (; k < deg; ++k) {
        int src = perm[b + k];
        float2 x = *(const float2*)&xl[(size_t)src * 128 + l * 2];
        float p = LEAKY(x.x + xrv.x) * attv.x + LEAKY(x.y + xrv.y) * attv.y;
        WREDUCE(p)
        float mn = fmaxf(m, p);
        float f  = expf(m - mn);
        float ex = expf(p - mn);
        den   = den   * f + ex;
        acc.x = acc.x * f + ex * x.x;
        acc.y = acc.y * f + ex * x.y;
        m = mn;
    }

    const float scale = (MODE == 0) ? 1.0f : 0.5f;
    const float r = scale / fmaxf(den, 1e-16f);
    float ox = acc.x * r, oy = acc.y * r;

    const size_t idx = (size_t)node * 128 + l * 2;
    if (MODE == 2) {
        ushort2 ph = *(const ushort2*)&hhi[idx];
        ushort2 pl = *(const ushort2*)&hlo[idx];
        ox += bf16tof(ph.x) + bf16tof(pl.x);
        oy += bf16tof(ph.y) + bf16tof(pl.y);
    }
    unsigned short hx = bf16rn(ox);
    unsigned short lx = bf16rn(ox - bf16tof(hx));
    unsigned short hy = bf16rn(oy);
    unsigned short ly = bf16rn(oy - bf16tof(hy));
    ushort2 vh; vh.x = hx; vh.y = hy;
    ushort2 vl; vl.x = lx; vl.y = ly;
    *(ushort2*)&hhi[idx] = vh;
    *(ushort2*)&hlo[idx] = vl;
}

// ---------------------------------------------------------------- pair MLP (MFMA gate)
__global__ __launch_bounds__(256) void mlp_fused(
        const unsigned short* __restrict__ hlhi, const unsigned short* __restrict__ hllo,
        const unsigned short* __restrict__ hmhi, const unsigned short* __restrict__ hmlo,
        const int* __restrict__ pairs, int P,
        const unsigned short* __restrict__ whi, const unsigned short* __restrict__ wlo,
        const float* __restrict__ bconst,
        const float* __restrict__ b_ll, const float* __restrict__ b_mm,
        const float* __restrict__ b_lm,
        const float* __restrict__ c1_W, const float* __restrict__ c1_b,
        const float* __restrict__ c2_W, const float* __restrict__ c2_b,
        const float* __restrict__ c3_W, const float* __restrict__ c3_b,
        float* __restrict__ out) {
    __shared__ float fus[64][132];
    __shared__ float h1s[64][68];
    const int t  = threadIdx.x;
    const int pb = blockIdx.x * 64;

    // ---- gate GEMM via MFMA bf16 hi/lo split ----
    {
        const int w = t >> 6, l = t & 63;
        const int lg = l >> 4, lr = l & 15;
        int pidx = pb + w * 16 + lr; if (pidx >= P) pidx = P - 1;
        const int r1 = pairs[pidx * 2 + 0];
        const int r2 = pairs[pidx * 2 + 1];

        f32x4 acc[8];
#pragma unroll
        for (int nt = 0; nt < 8; ++nt) acc[nt] = (f32x4){0.f, 0.f, 0.f, 0.f};

#pragma unroll
        for (int kt = 0; kt < 8; ++kt) {
            const unsigned short* Ahi = (kt < 4) ? hlhi : hmhi;
            const unsigned short* Alo = (kt < 4) ? hllo : hmlo;
            const int arow  = (kt < 4) ? r1 : r2;
            const int kbase = (kt & 3) * 32 + lg * 8;
            s16x8 ahi = *(const s16x8*)&Ahi[(size_t)arow * 128 + kbase];
            s16x8 alo = *(const s16x8*)&Alo[(size_t)arow * 128 + kbase];
#pragma unroll
            for (int nt = 0; nt < 8; ++nt) {
                const int boff = ((nt * 8 + kt) * 64 + l) * 8;
                s16x8 bhi = *(const s16x8*)&whi[boff];
                s16x8 blo = *(const s16x8*)&wlo[boff];
                acc[nt] = __builtin_amdgcn_mfma_f32_16x16x32_bf16(alo, bhi, acc[nt], 0, 0, 0);
                acc[nt] = __builtin_amdgcn_mfma_f32_16x16x32_bf16(ahi, blo, acc[nt], 0, 0, 0);
                acc[nt] = __builtin_amdgcn_mfma_f32_16x16x32_bf16(ahi, bhi, acc[nt], 0, 0, 0);
            }
        }
#pragma unroll
        for (int nt = 0; nt < 8; ++nt) {
            const int col = nt * 16 + lr;
#pragma unroll
            for (int r = 0; r < 4; ++r) {
                const int row = w * 16 + lg * 4 + r;
                float x  = acc[nt][r] + bconst[col];
                float rl = fmaxf(x, 0.0f);
                fus[row][col] = 1.0f / (1.0f + expf(-rl));
            }
        }
    }
    __syncthreads();

    // ---- fuse ----
    {
        const int p  = t >> 2;
        const int cb = (t & 3) * 32;
        int pidx = pb + p; if (pidx >= P) pidx = P - 1;
        const int r1 = pairs[pidx * 2 + 0];
        const int r2 = pairs[pidx * 2 + 1];
#pragma unroll
        for (int jj = 0; jj < 4; ++jj) {
            const int c = cb + jj * 8;
            s16x8 a1h = *(const s16x8*)&hlhi[(size_t)r1 * 128 + c];
            s16x8 a1l = *(const s16x8*)&hllo[(size_t)r1 * 128 + c];
            s16x8 a2h = *(const s16x8*)&hmhi[(size_t)r2 * 128 + c];
            s16x8 a2l = *(const s16x8*)&hmlo[(size_t)r2 * 128 + c];
            float fo[8];
#pragma unroll
            for (int q = 0; q < 8; ++q) {
                float g  = fus[p][c + q];
                float v1 = bf16tof((unsigned short)a1h[q]) + bf16tof((unsigned short)a1l[q])
                         + b_ll[c + q];
                float v2 = bf16tof((unsigned short)a2h[q]) + bf16tof((unsigned short)a2l[q])
                         + 0.5f * (b_mm[c + q] + b_lm[c + q]);
                fo[q] = g * v1 + (1.0f - g) * v2;
            }
            float4 w0 = {fo[0], fo[1], fo[2], fo[3]};
            float4 w1 = {fo[4], fo[5], fo[6], fo[7]};
            *(float4*)&fus[p][c + 0] = w0;
            *(float4*)&fus[p][c + 4] = w1;
        }
    }
    __syncthreads();

    // ---- c1 ----
    {
        const int p0 = (t >> 4) * 4;
        const int o0 = (t & 15) * 4;
        float acc[4][4] = {};
#pragma unroll 2
        for (int k0 = 0; k0 < 128; k0 += 4) {
            float4 a0 = *(const float4*)&fus[p0 + 0][k0];
            float4 a1 = *(const float4*)&fus[p0 + 1][k0];
            float4 a2 = *(const float4*)&fus[p0 + 2][k0];
            float4 a3 = *(const float4*)&fus[p0 + 3][k0];
            float4 w0 = *(const float4*)&c1_W[(k0 + 0) * 64 + o0];
            float4 w1 = *(const float4*)&c1_W[(k0 + 1) * 64 + o0];
            float4 w2 = *(const float4*)&c1_W[(k0 + 2) * 64 + o0];
            float4 w3 = *(const float4*)&c1_W[(k0 + 3) * 64 + o0];
            fma4(acc[0], a0, w0, w1, w2, w3);
            fma4(acc[1], a1, w0, w1, w2, w3);
            fma4(acc[2], a2, w0, w1, w2, w3);
            fma4(acc[3], a3, w0, w1, w2, w3);
        }
#pragma unroll
        for (int i = 0; i < 4; ++i)
#pragma unroll
            for (int n = 0; n < 4; ++n)
                h1s[p0 + i][o0 + n] = fmaxf(acc[i][n] + c1_b[o0 + n], 0.0f);
    }
    __syncthreads();

    // ---- c2 (overlays fus region, stride 36) ----
    float* h2 = &fus[0][0];
    {
        const int p0 = (t >> 3) * 2;
        const int o0 = (t & 7) * 4;
        float acc[2][4] = {};
#pragma unroll
        for (int k0 = 0; k0 < 64; k0 += 4) {
            float4 a0 = *(const float4*)&h1s[p0 + 0][k0];
            float4 a1 = *(const float4*)&h1s[p0 + 1][k0];
            float4 w0 = *(const float4*)&c2_W[(k0 + 0) * 32 + o0];
            float4 w1 = *(const float4*)&c2_W[(k0 + 1) * 32 + o0];
            float4 w2 = *(const float4*)&c2_W[(k0 + 2) * 32 + o0];
            float4 w3 = *(const float4*)&c2_W[(k0 + 3) * 32 + o0];
            fma4(acc[0], a0, w0, w1, w2, w3);
            fma4(acc[1], a1, w0, w1, w2, w3);
        }
        __syncthreads();
#pragma unroll
        for (int i = 0; i < 2; ++i)
#pragma unroll
            for (int n = 0; n < 4; ++n)
                h2[(p0 + i) * 36 + o0 + n] = fmaxf(acc[i][n] + c2_b[o0 + n], 0.0f);
    }
    __syncthreads();

    // ---- c3 ----
    if (t < 64) {
        int pi = pb + t;
        if (pi < P) {
            float s = c3_b[0];
#pragma unroll
            for (int k = 0; k < 32; ++k) s += h2[t * 36 + k] * c3_W[k];
            out[pi] = s;
        }
    }
}

// ---------------------------------------------------------------- launch
extern "C" void kernel_launch(void* const* d_in, const int* in_sizes, int n_in,
                              void* d_out, int out_size, void* d_ws, size_t ws_size,
                              hipStream_t stream) {
    const float* x_lnc  = (const float*)d_in[0];
    const float* x_mi   = (const float*)d_in[1];
    const float* Wl_ll  = (const float*)d_in[2];
    const float* Wr_ll  = (const float*)d_in[3];
    const float* att_ll = (const float*)d_in[4];
    const float* b_ll   = (const float*)d_in[5];
    const float* Wl_mm  = (const float*)d_in[6];
    const float* Wr_mm  = (const float*)d_in[7];
    const float* att_mm = (const float*)d_in[8];
    const float* b_mm   = (const float*)d_in[9];
    const float* Wl_lm  = (const float*)d_in[10];
    const float* Wr_lm  = (const float*)d_in[11];
    const float* att_lm = (const float*)d_in[12];
    const float* b_lm   = (const float*)d_in[13];
    const float* gate_W = (const float*)d_in[14];
    const float* gate_b = (const float*)d_in[15];
    const float* c1_W   = (const float*)d_in[16];
    const float* c1_b   = (const float*)d_in[17];
    const float* c2_W   = (const float*)d_in[18];
    const float* c2_b   = (const float*)d_in[19];
    const float* c3_W   = (const float*)d_in[20];
    const float* c3_b   = (const float*)d_in[21];
    const int* edge_ll  = (const int*)d_in[22];
    const int* edge_mm  = (const int*)d_in[23];
    const int* edge_lm  = (const int*)d_in[24];
    const int* pairs    = (const int*)d_in[25];

    const int N = in_sizes[0] / 256;    // 30000
    const int E = in_sizes[22] / 2;     // 480000
    const int P = in_sizes[25] / 2;     // 100000

    char* ws = (char*)d_ws;
    size_t o = 0;
    auto alloc = [&](size_t bytes) { char* p = ws + o; o += (bytes + 255) & ~(size_t)255; return p; };

    float* xl            = (float*)alloc((size_t)N * 128 * 4);
    float* xr            = (float*)alloc((size_t)N * 128 * 4);
    unsigned short* hlhi = (unsigned short*)alloc((size_t)N * 128 * 2);
    unsigned short* hllo = (unsigned short*)alloc((size_t)N * 128 * 2);
    unsigned short* hmhi = (unsigned short*)alloc((size_t)N * 128 * 2);
    unsigned short* hmlo = (unsigned short*)alloc((size_t)N * 128 * 2);
    int* perm            = (int*)alloc((size_t)E * 4);
    int* counts3         = (int*)alloc((size_t)3 * N * 4);
    int* base3           = (int*)alloc((size_t)3 * N * 4);
    int* cursor3         = (int*)alloc((size_t)3 * N * 4);
    unsigned short* wshi = (unsigned short*)alloc((size_t)7 * 32768 * 2);
    unsigned short* wslo = (unsigned short*)alloc((size_t)7 * 32768 * 2);
    float* bconst        = (float*)alloc(128 * 4);

    // weight plane index: 0 Wl_ll, 1 Wr_ll, 2 Wl_mm, 3 Wr_mm, 4 Wl_lm, 5 Wr_lm, 6 gate
    auto WHI = [&](int i) { return wshi + (size_t)i * 32768; };
    auto WLO = [&](int i) { return wslo + (size_t)i * 32768; };

    const int egrid     = (E + 255) / 256;
    const int gemm_grid = (N + 63) / 64;
    const int node_grid = (N + 3) / 4;

    split_w7<<<dim3(16, 7), 256, 0, stream>>>(Wl_ll, Wr_ll, Wl_mm, Wr_mm, Wl_lm, Wr_lm,
                                              gate_W, wshi, wslo);
    bconst_k<<<1, 128, 0, stream>>>(gate_W, gate_b, b_ll, b_mm, b_lm, bconst);
    zero_int<<<(3 * N + 255) / 256, 256, 0, stream>>>(counts3, 3 * N);
    hist3<<<dim3(egrid, 3), 256, 0, stream>>>(edge_ll, edge_mm, edge_lm, counts3, E, N);
    scan3<<<3, 1024, 0, stream>>>(counts3, base3, cursor3, N);

    // conv 0: ll
    scatter_edges<<<egrid, 256, 0, stream>>>(edge_ll, edge_ll + E, cursor3, perm, E);
    gemm_mfma<2><<<gemm_grid, 256, 0, stream>>>(x_lnc, WHI(0), WLO(0), WHI(1), WLO(1),
                                                xl, xr, N);
    node_gatv2<0><<<node_grid, 256, 0, stream>>>(xl, xr, att_ll, base3, counts3,
                                                 perm, hlhi, hllo, N);
    // conv 1: mm
    scatter_edges<<<egrid, 256, 0, stream>>>(edge_mm, edge_mm + E, cursor3 + N, perm, E);
    gemm_mfma<2><<<gemm_grid, 256, 0, stream>>>(x_mi, WHI(2), WLO(2), WHI(3), WLO(3),
                                                xl, xr, N);
    node_gatv2<1><<<node_grid, 256, 0, stream>>>(xl, xr, att_mm, base3 + N, counts3 + N,
                                                 perm, hmhi, hmlo, N);
    // conv 2: lm (two different A matrices -> paired single GEMMs in one launch)
    scatter_edges<<<egrid, 256, 0, stream>>>(edge_lm, edge_lm + E, cursor3 + 2 * N, perm, E);
    gemm_mfma_pair<<<dim3(gemm_grid, 2), 256, 0, stream>>>(x_lnc, x_mi,
                                                           WHI(4), WLO(4), WHI(5), WLO(5),
                                                           xl, xr, N);
    node_gatv2<2><<<node_grid, 256, 0, stream>>>(xl, xr, att_lm, base3 + 2 * N,
                                                 counts3 + 2 * N, perm, hmhi, hmlo, N);

    mlp_fused<<<(P + 63) / 64, 256, 0, stream>>>(hlhi, hllo, hmhi, hmlo, pairs, P,
                                                 WHI(6), WLO(6), bconst,
                                                 b_ll, b_mm, b_lm,
                                                 c1_W, c1_b, c2_W, c2_b, c3_W, c3_b,
                                                 (float*)d_out);
}